// Round 1
// baseline (495.275 us; speedup 1.0000x reference)
//
#include <hip/hip_runtime.h>
#include <hip/hip_bf16.h>
#include <math.h>

#define NN 40000
#define NE 640000
#define D 128
#define NCLS 40
#define FOUR_D 512

static inline int cdiv(int a, int b){ return (a + b - 1) / b; }

// ---------------- setup kernels ----------------

__global__ __launch_bounds__(256) void k_zero_int(int* __restrict__ p, int n) {
  int i = blockIdx.x * 256 + threadIdx.x;
  if (i < n) p[i] = 0;
}

__global__ __launch_bounds__(256) void k_count(const int* __restrict__ col,
                                               int* __restrict__ deg) {
  int i = blockIdx.x * 256 + threadIdx.x;
  if (i < NE) atomicAdd(&deg[col[i]], 1);
}

// hierarchical exclusive scan over deg[NN] -> rowptr
__global__ __launch_bounds__(256) void k_scan1(const int* __restrict__ cnt,
                                               int* __restrict__ excl,
                                               int* __restrict__ bsum) {
  __shared__ int sh[256];
  int b = blockIdx.x, t = threadIdx.x;
  int base = b * 1024 + t * 4;
  int v0 = (base + 0 < NN) ? cnt[base + 0] : 0;
  int v1 = (base + 1 < NN) ? cnt[base + 1] : 0;
  int v2 = (base + 2 < NN) ? cnt[base + 2] : 0;
  int v3 = (base + 3 < NN) ? cnt[base + 3] : 0;
  sh[t] = v0 + v1 + v2 + v3;
  __syncthreads();
  for (int off = 1; off < 256; off <<= 1) {
    int x = (t >= off) ? sh[t - off] : 0;
    __syncthreads();
    sh[t] += x;
    __syncthreads();
  }
  int pre = (t > 0) ? sh[t - 1] : 0;
  if (base + 0 < NN) excl[base + 0] = pre;  pre += v0;
  if (base + 1 < NN) excl[base + 1] = pre;  pre += v1;
  if (base + 2 < NN) excl[base + 2] = pre;  pre += v2;
  if (base + 3 < NN) excl[base + 3] = pre;
  if (t == 255) bsum[b] = sh[255];
}

__global__ void k_scan2(int* __restrict__ bsum, int nb, int* __restrict__ total_out) {
  int t = threadIdx.x;  // 64 threads
  __shared__ int sh[64];
  sh[t] = (t < nb) ? bsum[t] : 0;
  __syncthreads();
  if (t == 0) {
    int run = 0;
    for (int i = 0; i < nb; i++) { int v = sh[i]; sh[i] = run; run += v; }
    *total_out = run;
  }
  __syncthreads();
  if (t < nb) bsum[t] = sh[t];
}

__global__ __launch_bounds__(256) void k_scan3(int* __restrict__ rowptr,
                                               const int* __restrict__ bsum,
                                               const int* __restrict__ deg,
                                               int* __restrict__ cursor,
                                               float* __restrict__ dinv) {
  int i = blockIdx.x * 256 + threadIdx.x;
  if (i < NN) {
    int v = rowptr[i] + bsum[i >> 10];
    rowptr[i] = v;
    cursor[i] = v;
    dinv[i] = rsqrtf((float)(deg[i] + 1));  // +1 self-loop; always > 0
  }
}

__global__ __launch_bounds__(256) void k_fill(const int* __restrict__ row,
                                              const int* __restrict__ col,
                                              int* __restrict__ cursor,
                                              int* __restrict__ csr) {
  int i = blockIdx.x * 256 + threadIdx.x;
  if (i < NE) {
    int c = col[i];
    int p = atomicAdd(&cursor[c], 1);
    csr[p] = row[i];
  }
}

__global__ __launch_bounds__(256) void k_transpose(const float* __restrict__ in,
                                                   float* __restrict__ out, int R, int C) {
  int i = blockIdx.x * 256 + threadIdx.x;
  if (i < R * C) { int r = i / C, c = i - r * C; out[c * R + r] = in[i]; }
}

// ---------------- fp32 tiled GEMM: out[r][c] = sum_k A[r][k] * Wt[k][c] ----------------
// A: [NN x K], Wt: [K x 128] (pre-transposed weight), out: [NN x 128]
// Block: 256 threads, tile 64 rows x 128 cols, BK=32, per-thread 4x8.
template<int K, bool RELU, bool HASBIAS>
__global__ __launch_bounds__(256) void k_gemm(const float* __restrict__ A,
                                              const float* __restrict__ Wt,
                                              const float* __restrict__ bias,
                                              float* __restrict__ out) {
  __shared__ float As[64][36];    // +4 pad keeps float4 alignment (144B rows)
  __shared__ float Ws[32][128];
  int t = threadIdx.x;
  int tx = t & 15, ty = t >> 4;
  int row0 = blockIdx.x * 64;     // 40000 % 64 == 0 -> 625 blocks exactly
  float acc[4][8];
  #pragma unroll
  for (int i = 0; i < 4; i++)
    #pragma unroll
    for (int j = 0; j < 8; j++) acc[i][j] = 0.f;

  for (int kk = 0; kk < K; kk += 32) {
    __syncthreads();
    #pragma unroll
    for (int rep = 0; rep < 2; rep++) {
      int i = t + rep * 256;
      int r = i >> 3, kq = i & 7;
      float4 v = *(const float4*)&A[(size_t)(row0 + r) * K + kk + kq * 4];
      *(float4*)&As[r][kq * 4] = v;
    }
    #pragma unroll
    for (int rep = 0; rep < 4; rep++) {
      int i = t + rep * 256;
      int k = i >> 5, cq = i & 31;
      float4 v = *(const float4*)&Wt[(size_t)(kk + k) * 128 + cq * 4];
      *(float4*)&Ws[k][cq * 4] = v;
    }
    __syncthreads();
    #pragma unroll
    for (int k = 0; k < 32; k++) {
      float av[4];
      #pragma unroll
      for (int i = 0; i < 4; i++) av[i] = As[ty * 4 + i][k];
      float bv[8];
      *(float4*)&bv[0] = *(const float4*)&Ws[k][tx * 8];
      *(float4*)&bv[4] = *(const float4*)&Ws[k][tx * 8 + 4];
      #pragma unroll
      for (int i = 0; i < 4; i++)
        #pragma unroll
        for (int j = 0; j < 8; j++) acc[i][j] += av[i] * bv[j];
    }
  }

  float bb[8];
  if (HASBIAS) {
    #pragma unroll
    for (int j = 0; j < 8; j++) bb[j] = bias[tx * 8 + j];
  }
  #pragma unroll
  for (int i = 0; i < 4; i++) {
    int r = row0 + ty * 4 + i;
    float o[8];
    #pragma unroll
    for (int j = 0; j < 8; j++) {
      float v = acc[i][j];
      if (HASBIAS) v += bb[j];
      if (RELU) v = fmaxf(v, 0.f);
      o[j] = v;
    }
    *(float4*)&out[(size_t)r * 128 + tx * 8]     = *(float4*)&o[0];
    *(float4*)&out[(size_t)r * 128 + tx * 8 + 4] = *(float4*)&o[4];
  }
}

// ---------------- aggregation: one wave per node ----------------
// agg[n] = [mean(128) | add(128) | min(128) | max(128)]
__global__ __launch_bounds__(256) void k_agg(const float* __restrict__ h,
                                             const int* __restrict__ rowptr,
                                             const int* __restrict__ csr,
                                             const float* __restrict__ dinv,
                                             const int* __restrict__ deg,
                                             float* __restrict__ agg) {
  int wave = threadIdx.x >> 6, lane = threadIdx.x & 63;
  int nd = blockIdx.x * 4 + wave;   // grid 10000 * 4 waves == 40000 exactly
  float di = dinv[nd];
  float2 hv = *(const float2*)&h[(size_t)nd * D + lane * 2];
  float ns = di * di;               // self-loop norm = dinv[n]^2
  float sx = hv.x * ns, sy = hv.y * ns;
  float sumx = sx, sumy = sy;
  float mnx = sx, mny = sy, mxx = sx, mxy = sy;
  int e0 = rowptr[nd], e1 = rowptr[nd + 1];
  for (int e = e0; e < e1; e++) {
    int r = csr[e];
    float norm = dinv[r] * di;
    float2 v = *(const float2*)&h[(size_t)r * D + lane * 2];
    float vx = v.x * norm, vy = v.y * norm;
    sumx += vx; sumy += vy;
    mnx = fminf(mnx, vx); mny = fminf(mny, vy);
    mxx = fmaxf(mxx, vx); mxy = fmaxf(mxy, vy);
  }
  float invd = 1.f / (float)(deg[nd] + 1);
  size_t base = (size_t)nd * FOUR_D;
  float2 o;
  o.x = sumx * invd; o.y = sumy * invd;
  *(float2*)&agg[base +   0 + lane * 2] = o;
  o.x = sumx; o.y = sumy;
  *(float2*)&agg[base + 128 + lane * 2] = o;
  o.x = mnx; o.y = mny;
  *(float2*)&agg[base + 256 + lane * 2] = o;
  o.x = mxx; o.y = mxy;
  *(float2*)&agg[base + 384 + lane * 2] = o;
}

// ---------------- output head: wave per row, logits + log_softmax ----------------
__global__ __launch_bounds__(256) void k_out(const float* __restrict__ h,
                                             const float* __restrict__ Wt,   // [128][40]
                                             const float* __restrict__ b,
                                             float* __restrict__ out) {
  __shared__ float rowbuf[4][D];
  int wave = threadIdx.x >> 6, lane = threadIdx.x & 63;
  int r = blockIdx.x * 4 + wave;    // grid 10000 * 4 == 40000 exactly
  *(float2*)&rowbuf[wave][lane * 2] = *(const float2*)&h[(size_t)r * D + lane * 2];
  __syncthreads();
  float acc = 0.f;
  int c = lane;
  if (c < NCLS) {
    #pragma unroll 16
    for (int k = 0; k < D; k++) acc += rowbuf[wave][k] * Wt[k * NCLS + c];
    acc += b[c];
  }
  float v = (c < NCLS) ? acc : -INFINITY;
  float m = v;
  for (int off = 32; off; off >>= 1) m = fmaxf(m, __shfl_xor(m, off));
  float e = (c < NCLS) ? expf(v - m) : 0.f;
  float s = e;
  for (int off = 32; off; off >>= 1) s += __shfl_xor(s, off);
  if (c < NCLS) out[(size_t)r * NCLS + c] = v - m - logf(s);
}

// ---------------- launch ----------------
extern "C" void kernel_launch(void* const* d_in, const int* in_sizes, int n_in,
                              void* d_out, int out_size, void* d_ws, size_t ws_size,
                              hipStream_t stream) {
  const float* x    = (const float*)d_in[0];
  const int*   ei   = (const int*)  d_in[1];
  const float* W0   = (const float*)d_in[2];
  const float* C0   = (const float*)d_in[3];
  const float* b0   = (const float*)d_in[4];
  const float* W1   = (const float*)d_in[5];
  const float* C1   = (const float*)d_in[6];
  const float* b1   = (const float*)d_in[7];
  const float* Wout = (const float*)d_in[8];
  const float* bout = (const float*)d_in[9];
  float* out = (float*)d_out;

  char* ws = (char*)d_ws;
  size_t o = 0;
  auto take = [&](size_t bytes) -> char* {
    char* p = ws + o;
    o += (bytes + 255) & ~(size_t)255;
    return p;
  };
  int*   deg    = (int*)  take((size_t)NN * 4);
  int*   rowptr = (int*)  take((size_t)(NN + 1) * 4);
  int*   cursor = (int*)  take((size_t)NN * 4);
  int*   bsum   = (int*)  take(64 * 4);
  int*   csr    = (int*)  take((size_t)NE * 4);
  float* dinv   = (float*)take((size_t)NN * 4);
  float* Wt0    = (float*)take(128 * 128 * 4);
  float* Ct0    = (float*)take(512 * 128 * 4);
  float* Wt1    = (float*)take(128 * 128 * 4);
  float* Ct1    = (float*)take(512 * 128 * 4);
  float* Wtt    = (float*)take(128 * 40 * 4);
  float* bufA   = (float*)take((size_t)NN * 128 * 4);
  float* bufB   = (float*)take((size_t)NN * 512 * 4);
  float* bufC   = (float*)take((size_t)NN * 128 * 4);

  const int* row = ei;        // edge_index[0]
  const int* col = ei + NE;   // edge_index[1]

  // CSR by destination (col), self-loops handled analytically in k_agg
  k_zero_int<<<cdiv(NN, 256), 256, 0, stream>>>(deg, NN);
  k_count<<<cdiv(NE, 256), 256, 0, stream>>>(col, deg);
  k_scan1<<<40, 256, 0, stream>>>(deg, rowptr, bsum);
  k_scan2<<<1, 64, 0, stream>>>(bsum, 40, rowptr + NN);
  k_scan3<<<cdiv(NN, 256), 256, 0, stream>>>(rowptr, bsum, deg, cursor, dinv);
  k_fill<<<cdiv(NE, 256), 256, 0, stream>>>(row, col, cursor, csr);

  // pre-transpose weights for coalesced GEMM loads
  k_transpose<<<cdiv(128 * 128, 256), 256, 0, stream>>>(W0, Wt0, 128, 128);
  k_transpose<<<cdiv(128 * 512, 256), 256, 0, stream>>>(C0, Ct0, 128, 512);
  k_transpose<<<cdiv(128 * 128, 256), 256, 0, stream>>>(W1, Wt1, 128, 128);
  k_transpose<<<cdiv(128 * 512, 256), 256, 0, stream>>>(C1, Ct1, 128, 512);
  k_transpose<<<cdiv(40 * 128, 256), 256, 0, stream>>>(Wout, Wtt, 40, 128);

  // layer 0
  k_gemm<128, false, false><<<625, 256, 0, stream>>>(x, Wt0, nullptr, bufA);
  k_agg<<<10000, 256, 0, stream>>>(bufA, rowptr, csr, dinv, deg, bufB);
  k_gemm<512, true, true><<<625, 256, 0, stream>>>(bufB, Ct0, b0, bufC);
  // layer 1
  k_gemm<128, false, false><<<625, 256, 0, stream>>>(bufC, Wt1, nullptr, bufA);
  k_agg<<<10000, 256, 0, stream>>>(bufA, rowptr, csr, dinv, deg, bufB);
  k_gemm<512, true, true><<<625, 256, 0, stream>>>(bufB, Ct1, b1, bufC);
  // head + log_softmax
  k_out<<<10000, 256, 0, stream>>>(bufC, Wtt, bout, out);
}

// Round 2
// 352.625 us; speedup vs baseline: 1.4045x; 1.4045x over previous
//
#include <hip/hip_runtime.h>
#include <hip/hip_bf16.h>
#include <math.h>

#define NN 40000
#define NE 640000
#define D 128
#define NCLS 40
#define FOUR_D 512

typedef __bf16 bf16x8 __attribute__((ext_vector_type(8)));
typedef float  f32x4  __attribute__((ext_vector_type(4)));

static inline int cdiv(int a, int b){ return (a + b - 1) / b; }

// ---------------- setup kernels ----------------

__global__ __launch_bounds__(256) void k_zero_int(int* __restrict__ p, int n) {
  int i = blockIdx.x * 256 + threadIdx.x;
  if (i < n) p[i] = 0;
}

__global__ __launch_bounds__(256) void k_count(const int* __restrict__ col,
                                               int* __restrict__ deg) {
  int i = blockIdx.x * 256 + threadIdx.x;
  if (i < NE) atomicAdd(&deg[col[i]], 1);
}

__global__ __launch_bounds__(256) void k_scan1(const int* __restrict__ cnt,
                                               int* __restrict__ excl,
                                               int* __restrict__ bsum) {
  __shared__ int sh[256];
  int b = blockIdx.x, t = threadIdx.x;
  int base = b * 1024 + t * 4;
  int v0 = (base + 0 < NN) ? cnt[base + 0] : 0;
  int v1 = (base + 1 < NN) ? cnt[base + 1] : 0;
  int v2 = (base + 2 < NN) ? cnt[base + 2] : 0;
  int v3 = (base + 3 < NN) ? cnt[base + 3] : 0;
  sh[t] = v0 + v1 + v2 + v3;
  __syncthreads();
  for (int off = 1; off < 256; off <<= 1) {
    int x = (t >= off) ? sh[t - off] : 0;
    __syncthreads();
    sh[t] += x;
    __syncthreads();
  }
  int pre = (t > 0) ? sh[t - 1] : 0;
  if (base + 0 < NN) excl[base + 0] = pre;  pre += v0;
  if (base + 1 < NN) excl[base + 1] = pre;  pre += v1;
  if (base + 2 < NN) excl[base + 2] = pre;  pre += v2;
  if (base + 3 < NN) excl[base + 3] = pre;
  if (t == 255) bsum[b] = sh[255];
}

__global__ void k_scan2(int* __restrict__ bsum, int nb, int* __restrict__ total_out) {
  int t = threadIdx.x;  // 64 threads
  __shared__ int sh[64];
  sh[t] = (t < nb) ? bsum[t] : 0;
  __syncthreads();
  if (t == 0) {
    int run = 0;
    for (int i = 0; i < nb; i++) { int v = sh[i]; sh[i] = run; run += v; }
    *total_out = run;
  }
  __syncthreads();
  if (t < nb) bsum[t] = sh[t];
}

__global__ __launch_bounds__(256) void k_scan3(int* __restrict__ rowptr,
                                               const int* __restrict__ bsum,
                                               const int* __restrict__ deg,
                                               int* __restrict__ cursor,
                                               float* __restrict__ dinv) {
  int i = blockIdx.x * 256 + threadIdx.x;
  if (i < NN) {
    int v = rowptr[i] + bsum[i >> 10];
    rowptr[i] = v;
    cursor[i] = v;
    dinv[i] = rsqrtf((float)(deg[i] + 1));
  }
}

__global__ __launch_bounds__(256) void k_fill(const int* __restrict__ row,
                                              const int* __restrict__ col,
                                              int* __restrict__ cursor,
                                              int* __restrict__ csr) {
  int i = blockIdx.x * 256 + threadIdx.x;
  if (i < NE) {
    int c = col[i];
    int p = atomicAdd(&cursor[c], 1);
    csr[p] = row[i];
  }
}

__global__ __launch_bounds__(256) void k_transpose(const float* __restrict__ in,
                                                   float* __restrict__ out, int R, int C) {
  int i = blockIdx.x * 256 + threadIdx.x;
  if (i < R * C) { int r = i / C, c = i - r * C; out[c * R + r] = in[i]; }
}

// split fp32 weight -> bf16 hi + bf16 lo residual (keeps layout [n][k])
__global__ __launch_bounds__(256) void k_split(const float* __restrict__ w,
                                               __bf16* __restrict__ hi,
                                               __bf16* __restrict__ lo, int n) {
  int i = blockIdx.x * 256 + threadIdx.x;
  if (i < n) {
    float v = w[i];
    __bf16 h = (__bf16)v;
    hi[i] = h;
    lo[i] = (__bf16)(v - (float)h);
  }
}

// ---------------- MFMA GEMM: out[m][n] = sum_k A[m][k] * W[n][k] ----------------
// A: [NN x K] fp32 (split to bf16 hi/lo in-kernel). W pre-split bf16 [128][K].
// Block 256 thr = 4 waves (2x2), tile 64 rows x 128 cols, BK=64.
// LDS 16B chunks with XOR swizzle: chunk = row*8 + (slot ^ (row&7)).
template<int K, bool RELU, bool HASBIAS>
__global__ __launch_bounds__(256) void k_mm(const float* __restrict__ A,
                                            const __bf16* __restrict__ BhG,
                                            const __bf16* __restrict__ BlG,
                                            const float* __restrict__ bias,
                                            float* __restrict__ out) {
  __shared__ bf16x8 Ah[64 * 8], Al[64 * 8], Bh[128 * 8], Bl[128 * 8];
  int t = threadIdx.x;
  int lane = t & 63, wid = t >> 6;
  int wr = wid >> 1, wc = wid & 1;       // wave owns rows wr*32..+31, cols wc*64..+63
  int row0 = blockIdx.x * 64;            // 625 blocks * 64 == 40000 exactly

  f32x4 acc[2][4];
  #pragma unroll
  for (int m = 0; m < 2; m++)
    #pragma unroll
    for (int n = 0; n < 4; n++) acc[m][n] = (f32x4){0.f, 0.f, 0.f, 0.f};

  for (int k0 = 0; k0 < K; k0 += 64) {
    __syncthreads();
    // stage A: 64 rows x 64 k fp32 -> bf16 hi/lo, 512 chunks of 8 elems
    #pragma unroll
    for (int c = 0; c < 2; c++) {
      int id = t + c * 256;              // 0..511
      int r = id >> 3, q = id & 7;
      const float* src = &A[(size_t)(row0 + r) * K + k0 + q * 8];
      float4 v0 = *(const float4*)src;
      float4 v1 = *(const float4*)(src + 4);
      float vv[8] = {v0.x, v0.y, v0.z, v0.w, v1.x, v1.y, v1.z, v1.w};
      bf16x8 hi, lo;
      #pragma unroll
      for (int j = 0; j < 8; j++) {
        __bf16 h = (__bf16)vv[j];
        hi[j] = h;
        lo[j] = (__bf16)(vv[j] - (float)h);
      }
      int ch = r * 8 + (q ^ (r & 7));
      Ah[ch] = hi; Al[ch] = lo;
    }
    // stage B: 128 rows x 64 k bf16 (hi and lo), 1024 chunks each
    #pragma unroll
    for (int c = 0; c < 4; c++) {
      int id = t + c * 256;              // 0..1023
      int r = id >> 3, q = id & 7;
      int ch = r * 8 + (q ^ (r & 7));
      Bh[ch] = *(const bf16x8*)&BhG[(size_t)r * K + k0 + q * 8];
      Bl[ch] = *(const bf16x8*)&BlG[(size_t)r * K + k0 + q * 8];
    }
    __syncthreads();
    #pragma unroll
    for (int ks = 0; ks < 2; ks++) {
      bf16x8 ah[2], al[2], bh[4], bl[4];
      #pragma unroll
      for (int m = 0; m < 2; m++) {
        int row = wr * 32 + m * 16 + (lane & 15);
        int ch = row * 8 + ((ks * 4 + (lane >> 4)) ^ (row & 7));
        ah[m] = Ah[ch]; al[m] = Al[ch];
      }
      #pragma unroll
      for (int n = 0; n < 4; n++) {
        int row = wc * 64 + n * 16 + (lane & 15);
        int ch = row * 8 + ((ks * 4 + (lane >> 4)) ^ (row & 7));
        bh[n] = Bh[ch]; bl[n] = Bl[ch];
      }
      #pragma unroll
      for (int m = 0; m < 2; m++)
        #pragma unroll
        for (int n = 0; n < 4; n++) {
          acc[m][n] = __builtin_amdgcn_mfma_f32_16x16x32_bf16(ah[m], bh[n], acc[m][n], 0, 0, 0);
          acc[m][n] = __builtin_amdgcn_mfma_f32_16x16x32_bf16(ah[m], bl[n], acc[m][n], 0, 0, 0);
          acc[m][n] = __builtin_amdgcn_mfma_f32_16x16x32_bf16(al[m], bh[n], acc[m][n], 0, 0, 0);
        }
    }
  }

  // epilogue: C/D layout col = lane&15, row = (lane>>4)*4 + j
  #pragma unroll
  for (int m = 0; m < 2; m++)
    #pragma unroll
    for (int n = 0; n < 4; n++) {
      int col = wc * 64 + n * 16 + (lane & 15);
      int rbase = row0 + wr * 32 + m * 16 + (lane >> 4) * 4;
      float bv = HASBIAS ? bias[col] : 0.f;
      #pragma unroll
      for (int j = 0; j < 4; j++) {
        float v = acc[m][n][j] + bv;
        if (RELU) v = fmaxf(v, 0.f);
        out[(size_t)(rbase + j) * 128 + col] = v;
      }
    }
}

// ---------------- aggregation: one wave per node ----------------
__global__ __launch_bounds__(256) void k_agg(const float* __restrict__ h,
                                             const int* __restrict__ rowptr,
                                             const int* __restrict__ csr,
                                             const float* __restrict__ dinv,
                                             const int* __restrict__ deg,
                                             float* __restrict__ agg) {
  int wave = threadIdx.x >> 6, lane = threadIdx.x & 63;
  int nd = blockIdx.x * 4 + wave;
  float di = dinv[nd];
  float2 hv = *(const float2*)&h[(size_t)nd * D + lane * 2];
  float ns = di * di;
  float sx = hv.x * ns, sy = hv.y * ns;
  float sumx = sx, sumy = sy;
  float mnx = sx, mny = sy, mxx = sx, mxy = sy;
  int e0 = rowptr[nd], e1 = rowptr[nd + 1];
  for (int e = e0; e < e1; e++) {
    int r = csr[e];
    float norm = dinv[r] * di;
    float2 v = *(const float2*)&h[(size_t)r * D + lane * 2];
    float vx = v.x * norm, vy = v.y * norm;
    sumx += vx; sumy += vy;
    mnx = fminf(mnx, vx); mny = fminf(mny, vy);
    mxx = fmaxf(mxx, vx); mxy = fmaxf(mxy, vy);
  }
  float invd = 1.f / (float)(deg[nd] + 1);
  size_t base = (size_t)nd * FOUR_D;
  float2 o;
  o.x = sumx * invd; o.y = sumy * invd;
  *(float2*)&agg[base +   0 + lane * 2] = o;
  o.x = sumx; o.y = sumy;
  *(float2*)&agg[base + 128 + lane * 2] = o;
  o.x = mnx; o.y = mny;
  *(float2*)&agg[base + 256 + lane * 2] = o;
  o.x = mxx; o.y = mxy;
  *(float2*)&agg[base + 384 + lane * 2] = o;
}

// ---------------- output head ----------------
__global__ __launch_bounds__(256) void k_out(const float* __restrict__ h,
                                             const float* __restrict__ Wt,   // [128][40]
                                             const float* __restrict__ b,
                                             float* __restrict__ out) {
  __shared__ float rowbuf[4][D];
  int wave = threadIdx.x >> 6, lane = threadIdx.x & 63;
  int r = blockIdx.x * 4 + wave;
  *(float2*)&rowbuf[wave][lane * 2] = *(const float2*)&h[(size_t)r * D + lane * 2];
  __syncthreads();
  float acc = 0.f;
  int c = lane;
  if (c < NCLS) {
    #pragma unroll 16
    for (int k = 0; k < D; k++) acc += rowbuf[wave][k] * Wt[k * NCLS + c];
    acc += b[c];
  }
  float v = (c < NCLS) ? acc : -INFINITY;
  float m = v;
  for (int off = 32; off; off >>= 1) m = fmaxf(m, __shfl_xor(m, off));
  float e = (c < NCLS) ? expf(v - m) : 0.f;
  float s = e;
  for (int off = 32; off; off >>= 1) s += __shfl_xor(s, off);
  if (c < NCLS) out[(size_t)r * NCLS + c] = v - m - logf(s);
}

// ---------------- launch ----------------
extern "C" void kernel_launch(void* const* d_in, const int* in_sizes, int n_in,
                              void* d_out, int out_size, void* d_ws, size_t ws_size,
                              hipStream_t stream) {
  const float* x    = (const float*)d_in[0];
  const int*   ei   = (const int*)  d_in[1];
  const float* W0   = (const float*)d_in[2];
  const float* C0   = (const float*)d_in[3];
  const float* b0   = (const float*)d_in[4];
  const float* W1   = (const float*)d_in[5];
  const float* C1   = (const float*)d_in[6];
  const float* b1   = (const float*)d_in[7];
  const float* Wout = (const float*)d_in[8];
  const float* bout = (const float*)d_in[9];
  float* out = (float*)d_out;

  char* ws = (char*)d_ws;
  size_t o = 0;
  auto take = [&](size_t bytes) -> char* {
    char* p = ws + o;
    o += (bytes + 255) & ~(size_t)255;
    return p;
  };
  int*    deg    = (int*)   take((size_t)NN * 4);
  int*    rowptr = (int*)   take((size_t)(NN + 1) * 4);
  int*    cursor = (int*)   take((size_t)NN * 4);
  int*    bsum   = (int*)   take(64 * 4);
  int*    csr    = (int*)   take((size_t)NE * 4);
  float*  dinv   = (float*) take((size_t)NN * 4);
  __bf16* Whi0   = (__bf16*)take(128 * 128 * 2);
  __bf16* Wlo0   = (__bf16*)take(128 * 128 * 2);
  __bf16* Chi0   = (__bf16*)take(128 * 512 * 2);
  __bf16* Clo0   = (__bf16*)take(128 * 512 * 2);
  __bf16* Whi1   = (__bf16*)take(128 * 128 * 2);
  __bf16* Wlo1   = (__bf16*)take(128 * 128 * 2);
  __bf16* Chi1   = (__bf16*)take(128 * 512 * 2);
  __bf16* Clo1   = (__bf16*)take(128 * 512 * 2);
  float*  Wtt    = (float*) take(128 * 40 * 4);
  float*  bufA   = (float*) take((size_t)NN * 128 * 4);
  float*  bufB   = (float*) take((size_t)NN * 512 * 4);
  float*  bufC   = (float*) take((size_t)NN * 128 * 4);

  const int* row = ei;        // edge_index[0]
  const int* col = ei + NE;   // edge_index[1]

  // CSR by destination
  k_zero_int<<<cdiv(NN, 256), 256, 0, stream>>>(deg, NN);
  k_count<<<cdiv(NE, 256), 256, 0, stream>>>(col, deg);
  k_scan1<<<40, 256, 0, stream>>>(deg, rowptr, bsum);
  k_scan2<<<1, 64, 0, stream>>>(bsum, 40, rowptr + NN);
  k_scan3<<<cdiv(NN, 256), 256, 0, stream>>>(rowptr, bsum, deg, cursor, dinv);
  k_fill<<<cdiv(NE, 256), 256, 0, stream>>>(row, col, cursor, csr);

  // weight prep: split to bf16 hi/lo (layout [n][k] is MFMA B-operand native)
  k_split<<<cdiv(128 * 128, 256), 256, 0, stream>>>(W0, Whi0, Wlo0, 128 * 128);
  k_split<<<cdiv(128 * 512, 256), 256, 0, stream>>>(C0, Chi0, Clo0, 128 * 512);
  k_split<<<cdiv(128 * 128, 256), 256, 0, stream>>>(W1, Whi1, Wlo1, 128 * 128);
  k_split<<<cdiv(128 * 512, 256), 256, 0, stream>>>(C1, Chi1, Clo1, 128 * 512);
  k_transpose<<<cdiv(40 * 128, 256), 256, 0, stream>>>(Wout, Wtt, 40, 128);

  // layer 0
  k_mm<128, false, false><<<625, 256, 0, stream>>>(x, Whi0, Wlo0, nullptr, bufA);
  k_agg<<<10000, 256, 0, stream>>>(bufA, rowptr, csr, dinv, deg, bufB);
  k_mm<512, true, true><<<625, 256, 0, stream>>>(bufB, Chi0, Clo0, b0, bufC);
  // layer 1
  k_mm<128, false, false><<<625, 256, 0, stream>>>(bufC, Whi1, Wlo1, nullptr, bufA);
  k_agg<<<10000, 256, 0, stream>>>(bufA, rowptr, csr, dinv, deg, bufB);
  k_mm<512, true, true><<<625, 256, 0, stream>>>(bufB, Chi1, Clo1, b1, bufC);
  // head + log_softmax
  k_out<<<10000, 256, 0, stream>>>(bufC, Wtt, bout, out);
}

// Round 3
// 314.698 us; speedup vs baseline: 1.5738x; 1.1205x over previous
//
#include <hip/hip_runtime.h>
#include <hip/hip_bf16.h>
#include <math.h>

#define NN 40000
#define NE 640000
#define D 128
#define NCLS 40
#define FOUR_D 512

typedef __bf16 bf16x8 __attribute__((ext_vector_type(8)));
typedef __bf16 bf16x4 __attribute__((ext_vector_type(4)));
typedef float  f32x4  __attribute__((ext_vector_type(4)));

static inline int cdiv(int a, int b){ return (a + b - 1) / b; }

// ---------------- setup kernels ----------------

__global__ __launch_bounds__(256) void k_zero_int(int* __restrict__ p, int n) {
  int i = blockIdx.x * 256 + threadIdx.x;
  if (i < n) p[i] = 0;
}

__global__ __launch_bounds__(256) void k_count(const int* __restrict__ col,
                                               int* __restrict__ deg) {
  int i = blockIdx.x * 256 + threadIdx.x;
  if (i < NE) atomicAdd(&deg[col[i]], 1);
}

__global__ __launch_bounds__(256) void k_scan1(const int* __restrict__ cnt,
                                               int* __restrict__ excl,
                                               int* __restrict__ bsum) {
  __shared__ int sh[256];
  int b = blockIdx.x, t = threadIdx.x;
  int base = b * 1024 + t * 4;
  int v0 = (base + 0 < NN) ? cnt[base + 0] : 0;
  int v1 = (base + 1 < NN) ? cnt[base + 1] : 0;
  int v2 = (base + 2 < NN) ? cnt[base + 2] : 0;
  int v3 = (base + 3 < NN) ? cnt[base + 3] : 0;
  sh[t] = v0 + v1 + v2 + v3;
  __syncthreads();
  for (int off = 1; off < 256; off <<= 1) {
    int x = (t >= off) ? sh[t - off] : 0;
    __syncthreads();
    sh[t] += x;
    __syncthreads();
  }
  int pre = (t > 0) ? sh[t - 1] : 0;
  if (base + 0 < NN) excl[base + 0] = pre;  pre += v0;
  if (base + 1 < NN) excl[base + 1] = pre;  pre += v1;
  if (base + 2 < NN) excl[base + 2] = pre;  pre += v2;
  if (base + 3 < NN) excl[base + 3] = pre;
  if (t == 255) bsum[b] = sh[255];
}

__global__ void k_scan2(int* __restrict__ bsum, int nb, int* __restrict__ total_out) {
  int t = threadIdx.x;  // 64 threads
  __shared__ int sh[64];
  sh[t] = (t < nb) ? bsum[t] : 0;
  __syncthreads();
  if (t == 0) {
    int run = 0;
    for (int i = 0; i < nb; i++) { int v = sh[i]; sh[i] = run; run += v; }
    *total_out = run;
  }
  __syncthreads();
  if (t < nb) bsum[t] = sh[t];
}

__global__ __launch_bounds__(256) void k_scan3(int* __restrict__ rowptr,
                                               const int* __restrict__ bsum,
                                               const int* __restrict__ deg,
                                               int* __restrict__ cursor,
                                               float* __restrict__ dinv) {
  int i = blockIdx.x * 256 + threadIdx.x;
  if (i < NN) {
    int v = rowptr[i] + bsum[i >> 10];
    rowptr[i] = v;
    cursor[i] = v;
    dinv[i] = rsqrtf((float)(deg[i] + 1));
  }
}

__global__ __launch_bounds__(256) void k_fill(const int* __restrict__ row,
                                              const int* __restrict__ col,
                                              int* __restrict__ cursor,
                                              int* __restrict__ csr) {
  int i = blockIdx.x * 256 + threadIdx.x;
  if (i < NE) {
    int c = col[i];
    int p = atomicAdd(&cursor[c], 1);
    csr[p] = row[i];
  }
}

__global__ __launch_bounds__(256) void k_transpose(const float* __restrict__ in,
                                                   float* __restrict__ out, int R, int C) {
  int i = blockIdx.x * 256 + threadIdx.x;
  if (i < R * C) { int r = i / C, c = i - r * C; out[c * R + r] = in[i]; }
}

// split fp32 weight -> bf16 hi + bf16 lo residual (keeps layout [n][k])
__global__ __launch_bounds__(256) void k_split(const float* __restrict__ w,
                                               __bf16* __restrict__ hi,
                                               __bf16* __restrict__ lo, int n) {
  int i = blockIdx.x * 256 + threadIdx.x;
  if (i < n) {
    float v = w[i];
    __bf16 h = (__bf16)v;
    hi[i] = h;
    lo[i] = (__bf16)(v - (float)h);
  }
}

// ---------------- MFMA GEMM: out[m][n] = sum_k A[m][k] * W[n][k] ----------------
// ABF16: A is bf16 [NN x K] (2 MFMAs: A*Bhi + A*Blo). else A fp32, split hi/lo
// in staging (3 MFMAs). W pre-split bf16 [128][K].
// Block 256 thr = 4 waves (2x2), tile 64 rows x 128 cols, BK=64.
// LDS 16B chunks, XOR swizzle: chunk = row*8 + (slot ^ (row&7)).
template<int K, bool ABF16, bool OUTBF16, bool RELU, bool HASBIAS>
__global__ __launch_bounds__(256) void k_mm(const void* __restrict__ Av,
                                            const __bf16* __restrict__ BhG,
                                            const __bf16* __restrict__ BlG,
                                            const float* __restrict__ bias,
                                            void* __restrict__ outv) {
  __shared__ bf16x8 Ah[64 * 8];
  __shared__ bf16x8 Al[ABF16 ? 8 : 64 * 8];   // unused (small) in ABF16 mode
  __shared__ bf16x8 Bh[128 * 8], Bl[128 * 8];
  int t = threadIdx.x;
  int lane = t & 63, wid = t >> 6;
  int wr = wid >> 1, wc = wid & 1;
  int row0 = blockIdx.x * 64;            // 625 * 64 == 40000

  f32x4 acc[2][4];
  #pragma unroll
  for (int m = 0; m < 2; m++)
    #pragma unroll
    for (int n = 0; n < 4; n++) acc[m][n] = (f32x4){0.f, 0.f, 0.f, 0.f};

  for (int k0 = 0; k0 < K; k0 += 64) {
    __syncthreads();
    // stage A tile: 64 rows x 64 k
    #pragma unroll
    for (int c = 0; c < 2; c++) {
      int id = t + c * 256;              // 0..511
      int r = id >> 3, q = id & 7;
      int ch = r * 8 + (q ^ (r & 7));
      if constexpr (ABF16) {
        const __bf16* A = (const __bf16*)Av;
        Ah[ch] = *(const bf16x8*)&A[(size_t)(row0 + r) * K + k0 + q * 8];
      } else {
        const float* A = (const float*)Av;
        const float* src = &A[(size_t)(row0 + r) * K + k0 + q * 8];
        float4 v0 = *(const float4*)src;
        float4 v1 = *(const float4*)(src + 4);
        float vv[8] = {v0.x, v0.y, v0.z, v0.w, v1.x, v1.y, v1.z, v1.w};
        bf16x8 hi, lo;
        #pragma unroll
        for (int j = 0; j < 8; j++) {
          __bf16 h = (__bf16)vv[j];
          hi[j] = h;
          lo[j] = (__bf16)(vv[j] - (float)h);
        }
        Ah[ch] = hi; Al[ch] = lo;
      }
    }
    // stage B: 128 rows x 64 k (hi and lo)
    #pragma unroll
    for (int c = 0; c < 4; c++) {
      int id = t + c * 256;              // 0..1023
      int r = id >> 3, q = id & 7;
      int ch = r * 8 + (q ^ (r & 7));
      Bh[ch] = *(const bf16x8*)&BhG[(size_t)r * K + k0 + q * 8];
      Bl[ch] = *(const bf16x8*)&BlG[(size_t)r * K + k0 + q * 8];
    }
    __syncthreads();
    #pragma unroll
    for (int ks = 0; ks < 2; ks++) {
      bf16x8 ah[2], al[2], bh[4], bl[4];
      #pragma unroll
      for (int m = 0; m < 2; m++) {
        int row = wr * 32 + m * 16 + (lane & 15);
        int ch = row * 8 + ((ks * 4 + (lane >> 4)) ^ (row & 7));
        ah[m] = Ah[ch];
        if constexpr (!ABF16) al[m] = Al[ch];
      }
      #pragma unroll
      for (int n = 0; n < 4; n++) {
        int row = wc * 64 + n * 16 + (lane & 15);
        int ch = row * 8 + ((ks * 4 + (lane >> 4)) ^ (row & 7));
        bh[n] = Bh[ch]; bl[n] = Bl[ch];
      }
      #pragma unroll
      for (int m = 0; m < 2; m++)
        #pragma unroll
        for (int n = 0; n < 4; n++) {
          acc[m][n] = __builtin_amdgcn_mfma_f32_16x16x32_bf16(ah[m], bh[n], acc[m][n], 0, 0, 0);
          acc[m][n] = __builtin_amdgcn_mfma_f32_16x16x32_bf16(ah[m], bl[n], acc[m][n], 0, 0, 0);
          if constexpr (!ABF16)
            acc[m][n] = __builtin_amdgcn_mfma_f32_16x16x32_bf16(al[m], bh[n], acc[m][n], 0, 0, 0);
        }
    }
  }

  // epilogue: C/D layout col = lane&15, row = (lane>>4)*4 + j
  #pragma unroll
  for (int m = 0; m < 2; m++)
    #pragma unroll
    for (int n = 0; n < 4; n++) {
      int col = wc * 64 + n * 16 + (lane & 15);
      int rbase = row0 + wr * 32 + m * 16 + (lane >> 4) * 4;
      float bv = HASBIAS ? bias[col] : 0.f;
      #pragma unroll
      for (int j = 0; j < 4; j++) {
        float v = acc[m][n][j] + bv;
        if (RELU) v = fmaxf(v, 0.f);
        if constexpr (OUTBF16)
          ((__bf16*)outv)[(size_t)(rbase + j) * 128 + col] = (__bf16)v;
        else
          ((float*)outv)[(size_t)(rbase + j) * 128 + col] = v;
      }
    }
}

// ---------------- aggregation: 2 nodes per wave (32 lanes each, 8B/lane) ----------------
// h: bf16 [NN x 128], agg: bf16 [NN x 512] = [mean|add|min|max]
__global__ __launch_bounds__(256) void k_agg(const __bf16* __restrict__ h,
                                             const int* __restrict__ rowptr,
                                             const int* __restrict__ csr,
                                             const float* __restrict__ dinv,
                                             __bf16* __restrict__ agg) {
  int t = threadIdx.x;
  int half = t >> 5;                 // 0..7 node-slot within block
  int sl = t & 31;                   // lane within node: features sl*4..sl*4+3
  int nd = blockIdx.x * 8 + half;    // 5000 blocks * 8 == 40000
  float di = dinv[nd];
  float ns = di * di;                // self-loop norm AND 1/(deg+1)
  bf16x4 hv = *(const bf16x4*)&h[(size_t)nd * D + sl * 4];
  float s0 = (float)hv[0] * ns, s1 = (float)hv[1] * ns,
        s2 = (float)hv[2] * ns, s3 = (float)hv[3] * ns;
  float sum0 = s0, sum1 = s1, sum2 = s2, sum3 = s3;
  float mn0 = s0, mn1 = s1, mn2 = s2, mn3 = s3;
  float mx0 = s0, mx1 = s1, mx2 = s2, mx3 = s3;
  int e0 = rowptr[nd], e1 = rowptr[nd + 1];
  for (int e = e0; e < e1; e++) {
    int r = csr[e];
    float norm = dinv[r] * di;
    bf16x4 v = *(const bf16x4*)&h[(size_t)r * D + sl * 4];
    float v0 = (float)v[0] * norm, v1 = (float)v[1] * norm,
          v2 = (float)v[2] * norm, v3 = (float)v[3] * norm;
    sum0 += v0; sum1 += v1; sum2 += v2; sum3 += v3;
    mn0 = fminf(mn0, v0); mn1 = fminf(mn1, v1);
    mn2 = fminf(mn2, v2); mn3 = fminf(mn3, v3);
    mx0 = fmaxf(mx0, v0); mx1 = fmaxf(mx1, v1);
    mx2 = fmaxf(mx2, v2); mx3 = fmaxf(mx3, v3);
  }
  size_t base = (size_t)nd * FOUR_D + sl * 4;
  bf16x4 o;
  o[0] = (__bf16)(sum0 * ns); o[1] = (__bf16)(sum1 * ns);
  o[2] = (__bf16)(sum2 * ns); o[3] = (__bf16)(sum3 * ns);
  *(bf16x4*)&agg[base + 0] = o;
  o[0] = (__bf16)sum0; o[1] = (__bf16)sum1; o[2] = (__bf16)sum2; o[3] = (__bf16)sum3;
  *(bf16x4*)&agg[base + 128] = o;
  o[0] = (__bf16)mn0; o[1] = (__bf16)mn1; o[2] = (__bf16)mn2; o[3] = (__bf16)mn3;
  *(bf16x4*)&agg[base + 256] = o;
  o[0] = (__bf16)mx0; o[1] = (__bf16)mx1; o[2] = (__bf16)mx2; o[3] = (__bf16)mx3;
  *(bf16x4*)&agg[base + 384] = o;
}

// ---------------- output head ----------------
__global__ __launch_bounds__(256) void k_out(const float* __restrict__ h,
                                             const float* __restrict__ Wt,   // [128][40]
                                             const float* __restrict__ b,
                                             float* __restrict__ out) {
  __shared__ float rowbuf[4][D];
  int wave = threadIdx.x >> 6, lane = threadIdx.x & 63;
  int r = blockIdx.x * 4 + wave;
  *(float2*)&rowbuf[wave][lane * 2] = *(const float2*)&h[(size_t)r * D + lane * 2];
  __syncthreads();
  float acc = 0.f;
  int c = lane;
  if (c < NCLS) {
    #pragma unroll 16
    for (int k = 0; k < D; k++) acc += rowbuf[wave][k] * Wt[k * NCLS + c];
    acc += b[c];
  }
  float v = (c < NCLS) ? acc : -INFINITY;
  float m = v;
  for (int off = 32; off; off >>= 1) m = fmaxf(m, __shfl_xor(m, off));
  float e = (c < NCLS) ? expf(v - m) : 0.f;
  float s = e;
  for (int off = 32; off; off >>= 1) s += __shfl_xor(s, off);
  if (c < NCLS) out[(size_t)r * NCLS + c] = v - m - logf(s);
}

// ---------------- launch ----------------
extern "C" void kernel_launch(void* const* d_in, const int* in_sizes, int n_in,
                              void* d_out, int out_size, void* d_ws, size_t ws_size,
                              hipStream_t stream) {
  const float* x    = (const float*)d_in[0];
  const int*   ei   = (const int*)  d_in[1];
  const float* W0   = (const float*)d_in[2];
  const float* C0   = (const float*)d_in[3];
  const float* b0   = (const float*)d_in[4];
  const float* W1   = (const float*)d_in[5];
  const float* C1   = (const float*)d_in[6];
  const float* b1   = (const float*)d_in[7];
  const float* Wout = (const float*)d_in[8];
  const float* bout = (const float*)d_in[9];
  float* out = (float*)d_out;

  char* ws = (char*)d_ws;
  size_t o = 0;
  auto take = [&](size_t bytes) -> char* {
    char* p = ws + o;
    o += (bytes + 255) & ~(size_t)255;
    return p;
  };
  int*    deg    = (int*)   take((size_t)NN * 4);
  int*    rowptr = (int*)   take((size_t)(NN + 1) * 4);
  int*    cursor = (int*)   take((size_t)NN * 4);
  int*    bsum   = (int*)   take(64 * 4);
  int*    csr    = (int*)   take((size_t)NE * 4);
  float*  dinv   = (float*) take((size_t)NN * 4);
  __bf16* Whi0   = (__bf16*)take(128 * 128 * 2);
  __bf16* Wlo0   = (__bf16*)take(128 * 128 * 2);
  __bf16* Chi0   = (__bf16*)take(128 * 512 * 2);
  __bf16* Clo0   = (__bf16*)take(128 * 512 * 2);
  __bf16* Whi1   = (__bf16*)take(128 * 128 * 2);
  __bf16* Wlo1   = (__bf16*)take(128 * 128 * 2);
  __bf16* Chi1   = (__bf16*)take(128 * 512 * 2);
  __bf16* Clo1   = (__bf16*)take(128 * 512 * 2);
  float*  Wtt    = (float*) take(128 * 40 * 4);
  __bf16* bufA   = (__bf16*)take((size_t)NN * 128 * 2);   // h, bf16
  __bf16* bufB   = (__bf16*)take((size_t)NN * 512 * 2);   // agg, bf16
  float*  bufC   = (float*) take((size_t)NN * 128 * 4);   // layer out, fp32

  const int* row = ei;        // edge_index[0]
  const int* col = ei + NE;   // edge_index[1]

  // CSR by destination
  k_zero_int<<<cdiv(NN, 256), 256, 0, stream>>>(deg, NN);
  k_count<<<cdiv(NE, 256), 256, 0, stream>>>(col, deg);
  k_scan1<<<40, 256, 0, stream>>>(deg, rowptr, bsum);
  k_scan2<<<1, 64, 0, stream>>>(bsum, 40, rowptr + NN);
  k_scan3<<<cdiv(NN, 256), 256, 0, stream>>>(rowptr, bsum, deg, cursor, dinv);
  k_fill<<<cdiv(NE, 256), 256, 0, stream>>>(row, col, cursor, csr);

  // weight prep
  k_split<<<cdiv(128 * 128, 256), 256, 0, stream>>>(W0, Whi0, Wlo0, 128 * 128);
  k_split<<<cdiv(128 * 512, 256), 256, 0, stream>>>(C0, Chi0, Clo0, 128 * 512);
  k_split<<<cdiv(128 * 128, 256), 256, 0, stream>>>(W1, Whi1, Wlo1, 128 * 128);
  k_split<<<cdiv(128 * 512, 256), 256, 0, stream>>>(C1, Chi1, Clo1, 128 * 512);
  k_transpose<<<cdiv(40 * 128, 256), 256, 0, stream>>>(Wout, Wtt, 40, 128);

  // layer 0: lin (fp32 A -> bf16 h), agg (bf16), combine (bf16 A -> fp32)
  k_mm<128, false, true, false, false><<<625, 256, 0, stream>>>(x, Whi0, Wlo0, nullptr, bufA);
  k_agg<<<5000, 256, 0, stream>>>(bufA, rowptr, csr, dinv, bufB);
  k_mm<512, true, false, true, true><<<625, 256, 0, stream>>>(bufB, Chi0, Clo0, b0, bufC);
  // layer 1
  k_mm<128, false, true, false, false><<<625, 256, 0, stream>>>(bufC, Whi1, Wlo1, nullptr, bufA);
  k_agg<<<5000, 256, 0, stream>>>(bufA, rowptr, csr, dinv, bufB);
  k_mm<512, true, false, true, true><<<625, 256, 0, stream>>>(bufB, Chi1, Clo1, b1, bufC);
  // head + log_softmax
  k_out<<<10000, 256, 0, stream>>>(bufC, Wtt, bout, out);
}

// Round 4
// 245.218 us; speedup vs baseline: 2.0197x; 1.2833x over previous
//
#include <hip/hip_runtime.h>
#include <hip/hip_bf16.h>
#include <math.h>

#define NN 40000
#define NE 640000
#define D 128
#define NCLS 40
#define FOUR_D 512

typedef __bf16 bf16x8 __attribute__((ext_vector_type(8)));
typedef __bf16 bf16x4 __attribute__((ext_vector_type(4)));
typedef float  f32x4  __attribute__((ext_vector_type(4)));

static inline int cdiv(int a, int b){ return (a + b - 1) / b; }

// ---------------- setup kernels ----------------

__global__ __launch_bounds__(256) void k_zero_int(int* __restrict__ p, int n) {
  int i = blockIdx.x * 256 + threadIdx.x;
  if (i < n) p[i] = 0;
}

__global__ __launch_bounds__(256) void k_count(const int* __restrict__ col,
                                               int* __restrict__ deg) {
  int i = blockIdx.x * 256 + threadIdx.x;
  if (i < NE) atomicAdd(&deg[col[i]], 1);
}

__global__ __launch_bounds__(256) void k_scan1(const int* __restrict__ cnt,
                                               int* __restrict__ excl,
                                               int* __restrict__ bsum) {
  __shared__ int sh[256];
  int b = blockIdx.x, t = threadIdx.x;
  int base = b * 1024 + t * 4;
  int v0 = (base + 0 < NN) ? cnt[base + 0] : 0;
  int v1 = (base + 1 < NN) ? cnt[base + 1] : 0;
  int v2 = (base + 2 < NN) ? cnt[base + 2] : 0;
  int v3 = (base + 3 < NN) ? cnt[base + 3] : 0;
  sh[t] = v0 + v1 + v2 + v3;
  __syncthreads();
  for (int off = 1; off < 256; off <<= 1) {
    int x = (t >= off) ? sh[t - off] : 0;
    __syncthreads();
    sh[t] += x;
    __syncthreads();
  }
  int pre = (t > 0) ? sh[t - 1] : 0;
  if (base + 0 < NN) excl[base + 0] = pre;  pre += v0;
  if (base + 1 < NN) excl[base + 1] = pre;  pre += v1;
  if (base + 2 < NN) excl[base + 2] = pre;  pre += v2;
  if (base + 3 < NN) excl[base + 3] = pre;
  if (t == 255) bsum[b] = sh[255];
}

__global__ void k_scan2(int* __restrict__ bsum, int nb, int* __restrict__ total_out) {
  int t = threadIdx.x;  // 64 threads
  __shared__ int sh[64];
  sh[t] = (t < nb) ? bsum[t] : 0;
  __syncthreads();
  if (t == 0) {
    int run = 0;
    for (int i = 0; i < nb; i++) { int v = sh[i]; sh[i] = run; run += v; }
    *total_out = run;
  }
  __syncthreads();
  if (t < nb) bsum[t] = sh[t];
}

__global__ __launch_bounds__(256) void k_scan3(int* __restrict__ rowptr,
                                               const int* __restrict__ bsum,
                                               const int* __restrict__ deg,
                                               int* __restrict__ cursor,
                                               float* __restrict__ dinv) {
  int i = blockIdx.x * 256 + threadIdx.x;
  if (i < NN) {
    int v = rowptr[i] + bsum[i >> 10];
    rowptr[i] = v;
    cursor[i] = v;
    dinv[i] = rsqrtf((float)(deg[i] + 1));
  }
}

__global__ __launch_bounds__(256) void k_fill(const int* __restrict__ row,
                                              const int* __restrict__ col,
                                              int* __restrict__ cursor,
                                              int* __restrict__ csr) {
  int i = blockIdx.x * 256 + threadIdx.x;
  if (i < NE) {
    int c = col[i];
    int p = atomicAdd(&cursor[c], 1);
    csr[p] = row[i];
  }
}

__global__ __launch_bounds__(256) void k_transpose(const float* __restrict__ in,
                                                   float* __restrict__ out, int R, int C) {
  int i = blockIdx.x * 256 + threadIdx.x;
  if (i < R * C) { int r = i / C, c = i - r * C; out[c * R + r] = in[i]; }
}

// split fp32 weight -> bf16 hi + bf16 lo residual (keeps layout [n][k])
__global__ __launch_bounds__(256) void k_split(const float* __restrict__ w,
                                               __bf16* __restrict__ hi,
                                               __bf16* __restrict__ lo, int n) {
  int i = blockIdx.x * 256 + threadIdx.x;
  if (i < n) {
    float v = w[i];
    __bf16 h = (__bf16)v;
    hi[i] = h;
    lo[i] = (__bf16)(v - (float)h);
  }
}

// ---------------- MFMA GEMM: out[m][n] = sum_k A[m][k] * W[n][k] ----------------
template<int K, bool ABF16, bool OUTBF16, bool RELU, bool HASBIAS>
__global__ __launch_bounds__(256) void k_mm(const void* __restrict__ Av,
                                            const __bf16* __restrict__ BhG,
                                            const __bf16* __restrict__ BlG,
                                            const float* __restrict__ bias,
                                            void* __restrict__ outv) {
  __shared__ bf16x8 Ah[64 * 8];
  __shared__ bf16x8 Al[ABF16 ? 8 : 64 * 8];
  __shared__ bf16x8 Bh[128 * 8], Bl[128 * 8];
  int t = threadIdx.x;
  int lane = t & 63, wid = t >> 6;
  int wr = wid >> 1, wc = wid & 1;
  int row0 = blockIdx.x * 64;            // 625 * 64 == 40000

  f32x4 acc[2][4];
  #pragma unroll
  for (int m = 0; m < 2; m++)
    #pragma unroll
    for (int n = 0; n < 4; n++) acc[m][n] = (f32x4){0.f, 0.f, 0.f, 0.f};

  for (int k0 = 0; k0 < K; k0 += 64) {
    __syncthreads();
    #pragma unroll
    for (int c = 0; c < 2; c++) {
      int id = t + c * 256;              // 0..511
      int r = id >> 3, q = id & 7;
      int ch = r * 8 + (q ^ (r & 7));
      if constexpr (ABF16) {
        const __bf16* A = (const __bf16*)Av;
        Ah[ch] = *(const bf16x8*)&A[(size_t)(row0 + r) * K + k0 + q * 8];
      } else {
        const float* A = (const float*)Av;
        const float* src = &A[(size_t)(row0 + r) * K + k0 + q * 8];
        float4 v0 = *(const float4*)src;
        float4 v1 = *(const float4*)(src + 4);
        float vv[8] = {v0.x, v0.y, v0.z, v0.w, v1.x, v1.y, v1.z, v1.w};
        bf16x8 hi, lo;
        #pragma unroll
        for (int j = 0; j < 8; j++) {
          __bf16 h = (__bf16)vv[j];
          hi[j] = h;
          lo[j] = (__bf16)(vv[j] - (float)h);
        }
        Ah[ch] = hi; Al[ch] = lo;
      }
    }
    #pragma unroll
    for (int c = 0; c < 4; c++) {
      int id = t + c * 256;              // 0..1023
      int r = id >> 3, q = id & 7;
      int ch = r * 8 + (q ^ (r & 7));
      Bh[ch] = *(const bf16x8*)&BhG[(size_t)r * K + k0 + q * 8];
      Bl[ch] = *(const bf16x8*)&BlG[(size_t)r * K + k0 + q * 8];
    }
    __syncthreads();
    #pragma unroll
    for (int ks = 0; ks < 2; ks++) {
      bf16x8 ah[2], al[2], bh[4], bl[4];
      #pragma unroll
      for (int m = 0; m < 2; m++) {
        int row = wr * 32 + m * 16 + (lane & 15);
        int ch = row * 8 + ((ks * 4 + (lane >> 4)) ^ (row & 7));
        ah[m] = Ah[ch];
        if constexpr (!ABF16) al[m] = Al[ch];
      }
      #pragma unroll
      for (int n = 0; n < 4; n++) {
        int row = wc * 64 + n * 16 + (lane & 15);
        int ch = row * 8 + ((ks * 4 + (lane >> 4)) ^ (row & 7));
        bh[n] = Bh[ch]; bl[n] = Bl[ch];
      }
      #pragma unroll
      for (int m = 0; m < 2; m++)
        #pragma unroll
        for (int n = 0; n < 4; n++) {
          acc[m][n] = __builtin_amdgcn_mfma_f32_16x16x32_bf16(ah[m], bh[n], acc[m][n], 0, 0, 0);
          acc[m][n] = __builtin_amdgcn_mfma_f32_16x16x32_bf16(ah[m], bl[n], acc[m][n], 0, 0, 0);
          if constexpr (!ABF16)
            acc[m][n] = __builtin_amdgcn_mfma_f32_16x16x32_bf16(al[m], bh[n], acc[m][n], 0, 0, 0);
        }
    }
  }

  #pragma unroll
  for (int m = 0; m < 2; m++)
    #pragma unroll
    for (int n = 0; n < 4; n++) {
      int col = wc * 64 + n * 16 + (lane & 15);
      int rbase = row0 + wr * 32 + m * 16 + (lane >> 4) * 4;
      float bv = HASBIAS ? bias[col] : 0.f;
      #pragma unroll
      for (int j = 0; j < 4; j++) {
        float v = acc[m][n][j] + bv;
        if (RELU) v = fmaxf(v, 0.f);
        if constexpr (OUTBF16)
          ((__bf16*)outv)[(size_t)(rbase + j) * 128 + col] = (__bf16)v;
        else
          ((float*)outv)[(size_t)(rbase + j) * 128 + col] = v;
      }
    }
}

// ---------------- aggregation: 16 lanes per node, 4 nodes/wave ----------------
// Edge indices batch-loaded (lane sl holds edge sl of the chunk); inner loop
// broadcasts from registers via shfl and keeps 4 row-gathers in flight.
// h: bf16 [NN x 128], agg: bf16 [NN x 512] = [mean|add|min|max]
__global__ __launch_bounds__(256) void k_agg(const __bf16* __restrict__ h,
                                             const int* __restrict__ rowptr,
                                             const int* __restrict__ csr,
                                             const float* __restrict__ dinv,
                                             __bf16* __restrict__ agg) {
  int t = threadIdx.x;
  int g = t >> 4;                    // 0..15 group in block
  int sl = t & 15;                   // lane in group; features sl*8..sl*8+7
  int nd = blockIdx.x * 16 + g;      // 2500 blocks * 16 == 40000
  float di = dinv[nd];
  float ns = di * di;                // self-loop norm AND 1/(deg+1)
  bf16x8 hv = *(const bf16x8*)&h[(size_t)nd * D + sl * 8];
  float sum[8], mn[8], mx[8];
  #pragma unroll
  for (int q = 0; q < 8; q++) {
    float v = (float)hv[q] * ns;
    sum[q] = v; mn[q] = v; mx[q] = v;
  }
  int e0 = rowptr[nd], e1 = rowptr[nd + 1];

  for (int eb = e0; eb < e1; eb += 16) {
    int rem = e1 - eb; if (rem > 16) rem = 16;
    int le = eb + (sl < rem ? sl : rem - 1);
    int re = csr[le];                    // lane sl holds edge sl's source
    float nr = dinv[re] * di;            // lane sl holds edge sl's norm

    int j = 0;
    for (; j + 4 <= rem; j += 4) {
      int r0 = __shfl(re, j + 0, 16), r1 = __shfl(re, j + 1, 16);
      int r2 = __shfl(re, j + 2, 16), r3 = __shfl(re, j + 3, 16);
      float n0 = __shfl(nr, j + 0, 16), n1 = __shfl(nr, j + 1, 16);
      float n2 = __shfl(nr, j + 2, 16), n3 = __shfl(nr, j + 3, 16);
      bf16x8 v0 = *(const bf16x8*)&h[(size_t)r0 * D + sl * 8];
      bf16x8 v1 = *(const bf16x8*)&h[(size_t)r1 * D + sl * 8];
      bf16x8 v2 = *(const bf16x8*)&h[(size_t)r2 * D + sl * 8];
      bf16x8 v3 = *(const bf16x8*)&h[(size_t)r3 * D + sl * 8];
      #pragma unroll
      for (int q = 0; q < 8; q++) {
        float a0 = (float)v0[q] * n0;
        sum[q] += a0; mn[q] = fminf(mn[q], a0); mx[q] = fmaxf(mx[q], a0);
        float a1 = (float)v1[q] * n1;
        sum[q] += a1; mn[q] = fminf(mn[q], a1); mx[q] = fmaxf(mx[q], a1);
        float a2 = (float)v2[q] * n2;
        sum[q] += a2; mn[q] = fminf(mn[q], a2); mx[q] = fmaxf(mx[q], a2);
        float a3 = (float)v3[q] * n3;
        sum[q] += a3; mn[q] = fminf(mn[q], a3); mx[q] = fmaxf(mx[q], a3);
      }
    }
    for (; j < rem; j++) {
      int r0 = __shfl(re, j, 16);
      float n0 = __shfl(nr, j, 16);
      bf16x8 v0 = *(const bf16x8*)&h[(size_t)r0 * D + sl * 8];
      #pragma unroll
      for (int q = 0; q < 8; q++) {
        float a0 = (float)v0[q] * n0;
        sum[q] += a0; mn[q] = fminf(mn[q], a0); mx[q] = fmaxf(mx[q], a0);
      }
    }
  }

  size_t base = (size_t)nd * FOUR_D + sl * 8;
  bf16x8 o;
  #pragma unroll
  for (int q = 0; q < 8; q++) o[q] = (__bf16)(sum[q] * ns);
  *(bf16x8*)&agg[base + 0] = o;
  #pragma unroll
  for (int q = 0; q < 8; q++) o[q] = (__bf16)sum[q];
  *(bf16x8*)&agg[base + 128] = o;
  #pragma unroll
  for (int q = 0; q < 8; q++) o[q] = (__bf16)mn[q];
  *(bf16x8*)&agg[base + 256] = o;
  #pragma unroll
  for (int q = 0; q < 8; q++) o[q] = (__bf16)mx[q];
  *(bf16x8*)&agg[base + 384] = o;
}

// ---------------- output head ----------------
__global__ __launch_bounds__(256) void k_out(const float* __restrict__ h,
                                             const float* __restrict__ Wt,   // [128][40]
                                             const float* __restrict__ b,
                                             float* __restrict__ out) {
  __shared__ float rowbuf[4][D];
  int wave = threadIdx.x >> 6, lane = threadIdx.x & 63;
  int r = blockIdx.x * 4 + wave;
  *(float2*)&rowbuf[wave][lane * 2] = *(const float2*)&h[(size_t)r * D + lane * 2];
  __syncthreads();
  float acc = 0.f;
  int c = lane;
  if (c < NCLS) {
    #pragma unroll 16
    for (int k = 0; k < D; k++) acc += rowbuf[wave][k] * Wt[k * NCLS + c];
    acc += b[c];
  }
  float v = (c < NCLS) ? acc : -INFINITY;
  float m = v;
  for (int off = 32; off; off >>= 1) m = fmaxf(m, __shfl_xor(m, off));
  float e = (c < NCLS) ? expf(v - m) : 0.f;
  float s = e;
  for (int off = 32; off; off >>= 1) s += __shfl_xor(s, off);
  if (c < NCLS) out[(size_t)r * NCLS + c] = v - m - logf(s);
}

// ---------------- launch ----------------
extern "C" void kernel_launch(void* const* d_in, const int* in_sizes, int n_in,
                              void* d_out, int out_size, void* d_ws, size_t ws_size,
                              hipStream_t stream) {
  const float* x    = (const float*)d_in[0];
  const int*   ei   = (const int*)  d_in[1];
  const float* W0   = (const float*)d_in[2];
  const float* C0   = (const float*)d_in[3];
  const float* b0   = (const float*)d_in[4];
  const float* W1   = (const float*)d_in[5];
  const float* C1   = (const float*)d_in[6];
  const float* b1   = (const float*)d_in[7];
  const float* Wout = (const float*)d_in[8];
  const float* bout = (const float*)d_in[9];
  float* out = (float*)d_out;

  char* ws = (char*)d_ws;
  size_t o = 0;
  auto take = [&](size_t bytes) -> char* {
    char* p = ws + o;
    o += (bytes + 255) & ~(size_t)255;
    return p;
  };
  int*    deg    = (int*)   take((size_t)NN * 4);
  int*    rowptr = (int*)   take((size_t)(NN + 1) * 4);
  int*    cursor = (int*)   take((size_t)NN * 4);
  int*    bsum   = (int*)   take(64 * 4);
  int*    csr    = (int*)   take((size_t)NE * 4);
  float*  dinv   = (float*) take((size_t)NN * 4);
  __bf16* Whi0   = (__bf16*)take(128 * 128 * 2);
  __bf16* Wlo0   = (__bf16*)take(128 * 128 * 2);
  __bf16* Chi0   = (__bf16*)take(128 * 512 * 2);
  __bf16* Clo0   = (__bf16*)take(128 * 512 * 2);
  __bf16* Whi1   = (__bf16*)take(128 * 128 * 2);
  __bf16* Wlo1   = (__bf16*)take(128 * 128 * 2);
  __bf16* Chi1   = (__bf16*)take(128 * 512 * 2);
  __bf16* Clo1   = (__bf16*)take(128 * 512 * 2);
  float*  Wtt    = (float*) take(128 * 40 * 4);
  __bf16* bufA   = (__bf16*)take((size_t)NN * 128 * 2);   // h, bf16
  __bf16* bufB   = (__bf16*)take((size_t)NN * 512 * 2);   // agg, bf16
  float*  bufC   = (float*) take((size_t)NN * 128 * 4);   // layer out, fp32

  const int* row = ei;        // edge_index[0]
  const int* col = ei + NE;   // edge_index[1]

  // CSR by destination
  k_zero_int<<<cdiv(NN, 256), 256, 0, stream>>>(deg, NN);
  k_count<<<cdiv(NE, 256), 256, 0, stream>>>(col, deg);
  k_scan1<<<40, 256, 0, stream>>>(deg, rowptr, bsum);
  k_scan2<<<1, 64, 0, stream>>>(bsum, 40, rowptr + NN);
  k_scan3<<<cdiv(NN, 256), 256, 0, stream>>>(rowptr, bsum, deg, cursor, dinv);
  k_fill<<<cdiv(NE, 256), 256, 0, stream>>>(row, col, cursor, csr);

  // weight prep
  k_split<<<cdiv(128 * 128, 256), 256, 0, stream>>>(W0, Whi0, Wlo0, 128 * 128);
  k_split<<<cdiv(128 * 512, 256), 256, 0, stream>>>(C0, Chi0, Clo0, 128 * 512);
  k_split<<<cdiv(128 * 128, 256), 256, 0, stream>>>(W1, Whi1, Wlo1, 128 * 128);
  k_split<<<cdiv(128 * 512, 256), 256, 0, stream>>>(C1, Chi1, Clo1, 128 * 512);
  k_transpose<<<cdiv(40 * 128, 256), 256, 0, stream>>>(Wout, Wtt, 40, 128);

  // layer 0: lin (fp32 A -> bf16 h), agg (bf16), combine (bf16 A -> fp32)
  k_mm<128, false, true, false, false><<<625, 256, 0, stream>>>(x, Whi0, Wlo0, nullptr, bufA);
  k_agg<<<2500, 256, 0, stream>>>(bufA, rowptr, csr, dinv, bufB);
  k_mm<512, true, false, true, true><<<625, 256, 0, stream>>>(bufB, Chi0, Clo0, b0, bufC);
  // layer 1
  k_mm<128, false, true, false, false><<<625, 256, 0, stream>>>(bufC, Whi1, Wlo1, nullptr, bufA);
  k_agg<<<2500, 256, 0, stream>>>(bufA, rowptr, csr, dinv, bufB);
  k_mm<512, true, false, true, true><<<625, 256, 0, stream>>>(bufB, Chi1, Clo1, b1, bufC);
  // head + log_softmax
  k_out<<<10000, 256, 0, stream>>>(bufC, Wtt, bout, out);
}

// Round 5
// 211.049 us; speedup vs baseline: 2.3467x; 1.1619x over previous
//
#include <hip/hip_runtime.h>
#include <hip/hip_bf16.h>
#include <math.h>

#define NN 40000
#define NE 640000
#define D 128
#define NCLS 40
#define FOUR_D 512

typedef __bf16 bf16x8 __attribute__((ext_vector_type(8)));
typedef __bf16 bf16x4 __attribute__((ext_vector_type(4)));
typedef float  f32x4  __attribute__((ext_vector_type(4)));

static inline int cdiv(int a, int b){ return (a + b - 1) / b; }

// ---------------- setup kernels ----------------

__global__ __launch_bounds__(256) void k_zero_int(int* __restrict__ p, int n) {
  int i = blockIdx.x * 256 + threadIdx.x;
  if (i < n) p[i] = 0;
}

__global__ __launch_bounds__(256) void k_count(const int* __restrict__ col,
                                               int* __restrict__ deg) {
  int i = blockIdx.x * 256 + threadIdx.x;
  if (i < NE) atomicAdd(&deg[col[i]], 1);
}

__global__ __launch_bounds__(256) void k_scan1(const int* __restrict__ cnt,
                                               int* __restrict__ excl,
                                               int* __restrict__ bsum) {
  __shared__ int sh[256];
  int b = blockIdx.x, t = threadIdx.x;
  int base = b * 1024 + t * 4;
  int v0 = (base + 0 < NN) ? cnt[base + 0] : 0;
  int v1 = (base + 1 < NN) ? cnt[base + 1] : 0;
  int v2 = (base + 2 < NN) ? cnt[base + 2] : 0;
  int v3 = (base + 3 < NN) ? cnt[base + 3] : 0;
  sh[t] = v0 + v1 + v2 + v3;
  __syncthreads();
  for (int off = 1; off < 256; off <<= 1) {
    int x = (t >= off) ? sh[t - off] : 0;
    __syncthreads();
    sh[t] += x;
    __syncthreads();
  }
  int pre = (t > 0) ? sh[t - 1] : 0;
  if (base + 0 < NN) excl[base + 0] = pre;  pre += v0;
  if (base + 1 < NN) excl[base + 1] = pre;  pre += v1;
  if (base + 2 < NN) excl[base + 2] = pre;  pre += v2;
  if (base + 3 < NN) excl[base + 3] = pre;
  if (t == 255) bsum[b] = sh[255];
}

__global__ void k_scan2(int* __restrict__ bsum, int nb, int* __restrict__ total_out) {
  int t = threadIdx.x;  // 64 threads
  __shared__ int sh[64];
  sh[t] = (t < nb) ? bsum[t] : 0;
  __syncthreads();
  if (t == 0) {
    int run = 0;
    for (int i = 0; i < nb; i++) { int v = sh[i]; sh[i] = run; run += v; }
    *total_out = run;
  }
  __syncthreads();
  if (t < nb) bsum[t] = sh[t];
}

__global__ __launch_bounds__(256) void k_scan3(int* __restrict__ rowptr,
                                               const int* __restrict__ bsum,
                                               const int* __restrict__ deg,
                                               int* __restrict__ cursor,
                                               float* __restrict__ dinv) {
  int i = blockIdx.x * 256 + threadIdx.x;
  if (i < NN) {
    int v = rowptr[i] + bsum[i >> 10];
    rowptr[i] = v;
    cursor[i] = v;
    dinv[i] = rsqrtf((float)(deg[i] + 1));
  }
}

__global__ __launch_bounds__(256) void k_fill(const int* __restrict__ row,
                                              const int* __restrict__ col,
                                              int* __restrict__ cursor,
                                              int* __restrict__ csr) {
  int i = blockIdx.x * 256 + threadIdx.x;
  if (i < NE) {
    int c = col[i];
    int p = atomicAdd(&cursor[c], 1);
    csr[p] = row[i];
  }
}

// split all 5 weight tensors fp32 -> bf16 hi/lo in one dispatch
// sizes: W0 16384, C0 65536, W1 16384, C1 65536, Wout 5120  (total 168960)
__global__ __launch_bounds__(256) void k_splitall(const float* __restrict__ W0, __bf16* h0, __bf16* l0,
                                                  const float* __restrict__ C0, __bf16* h1, __bf16* l1,
                                                  const float* __restrict__ W1, __bf16* h2, __bf16* l2,
                                                  const float* __restrict__ C1, __bf16* h3, __bf16* l3,
                                                  const float* __restrict__ WO, __bf16* h4, __bf16* l4) {
  int i = blockIdx.x * 256 + threadIdx.x;
  const float* src; __bf16* dh; __bf16* dl; int off;
  if      (i < 16384)  { src = W0; dh = h0; dl = l0; off = i; }
  else if (i < 81920)  { src = C0; dh = h1; dl = l1; off = i - 16384; }
  else if (i < 98304)  { src = W1; dh = h2; dl = l2; off = i - 81920; }
  else if (i < 163840) { src = C1; dh = h3; dl = l3; off = i - 98304; }
  else if (i < 168960) { src = WO; dh = h4; dl = l4; off = i - 163840; }
  else return;
  float v = src[off];
  __bf16 h = (__bf16)v;
  dh[off] = h;
  dl[off] = (__bf16)(v - (float)h);
}

// ---------------- MFMA GEMM: out[m][n] = sum_k A[m][k] * W[n][k] ----------------
template<int K, bool ABF16, bool OUTBF16, bool RELU, bool HASBIAS>
__global__ __launch_bounds__(256) void k_mm(const void* __restrict__ Av,
                                            const __bf16* __restrict__ BhG,
                                            const __bf16* __restrict__ BlG,
                                            const float* __restrict__ bias,
                                            void* __restrict__ outv) {
  __shared__ bf16x8 Ah[64 * 8];
  __shared__ bf16x8 Al[ABF16 ? 8 : 64 * 8];
  __shared__ bf16x8 Bh[128 * 8], Bl[128 * 8];
  int t = threadIdx.x;
  int lane = t & 63, wid = t >> 6;
  int wr = wid >> 1, wc = wid & 1;
  int row0 = blockIdx.x * 64;            // 625 * 64 == 40000

  f32x4 acc[2][4];
  #pragma unroll
  for (int m = 0; m < 2; m++)
    #pragma unroll
    for (int n = 0; n < 4; n++) acc[m][n] = (f32x4){0.f, 0.f, 0.f, 0.f};

  for (int k0 = 0; k0 < K; k0 += 64) {
    __syncthreads();
    #pragma unroll
    for (int c = 0; c < 2; c++) {
      int id = t + c * 256;              // 0..511
      int r = id >> 3, q = id & 7;
      int ch = r * 8 + (q ^ (r & 7));
      if constexpr (ABF16) {
        const __bf16* A = (const __bf16*)Av;
        Ah[ch] = *(const bf16x8*)&A[(size_t)(row0 + r) * K + k0 + q * 8];
      } else {
        const float* A = (const float*)Av;
        const float* src = &A[(size_t)(row0 + r) * K + k0 + q * 8];
        float4 v0 = *(const float4*)src;
        float4 v1 = *(const float4*)(src + 4);
        float vv[8] = {v0.x, v0.y, v0.z, v0.w, v1.x, v1.y, v1.z, v1.w};
        bf16x8 hi, lo;
        #pragma unroll
        for (int j = 0; j < 8; j++) {
          __bf16 h = (__bf16)vv[j];
          hi[j] = h;
          lo[j] = (__bf16)(vv[j] - (float)h);
        }
        Ah[ch] = hi; Al[ch] = lo;
      }
    }
    #pragma unroll
    for (int c = 0; c < 4; c++) {
      int id = t + c * 256;              // 0..1023
      int r = id >> 3, q = id & 7;
      int ch = r * 8 + (q ^ (r & 7));
      Bh[ch] = *(const bf16x8*)&BhG[(size_t)r * K + k0 + q * 8];
      Bl[ch] = *(const bf16x8*)&BlG[(size_t)r * K + k0 + q * 8];
    }
    __syncthreads();
    #pragma unroll
    for (int ks = 0; ks < 2; ks++) {
      bf16x8 ah[2], al[2], bh[4], bl[4];
      #pragma unroll
      for (int m = 0; m < 2; m++) {
        int row = wr * 32 + m * 16 + (lane & 15);
        int ch = row * 8 + ((ks * 4 + (lane >> 4)) ^ (row & 7));
        ah[m] = Ah[ch];
        if constexpr (!ABF16) al[m] = Al[ch];
      }
      #pragma unroll
      for (int n = 0; n < 4; n++) {
        int row = wc * 64 + n * 16 + (lane & 15);
        int ch = row * 8 + ((ks * 4 + (lane >> 4)) ^ (row & 7));
        bh[n] = Bh[ch]; bl[n] = Bl[ch];
      }
      #pragma unroll
      for (int m = 0; m < 2; m++)
        #pragma unroll
        for (int n = 0; n < 4; n++) {
          acc[m][n] = __builtin_amdgcn_mfma_f32_16x16x32_bf16(ah[m], bh[n], acc[m][n], 0, 0, 0);
          acc[m][n] = __builtin_amdgcn_mfma_f32_16x16x32_bf16(ah[m], bl[n], acc[m][n], 0, 0, 0);
          if constexpr (!ABF16)
            acc[m][n] = __builtin_amdgcn_mfma_f32_16x16x32_bf16(al[m], bh[n], acc[m][n], 0, 0, 0);
        }
    }
  }

  #pragma unroll
  for (int m = 0; m < 2; m++)
    #pragma unroll
    for (int n = 0; n < 4; n++) {
      int col = wc * 64 + n * 16 + (lane & 15);
      int rbase = row0 + wr * 32 + m * 16 + (lane >> 4) * 4;
      float bv = HASBIAS ? bias[col] : 0.f;
      #pragma unroll
      for (int j = 0; j < 4; j++) {
        float v = acc[m][n][j] + bv;
        if (RELU) v = fmaxf(v, 0.f);
        if constexpr (OUTBF16)
          ((__bf16*)outv)[(size_t)(rbase + j) * 128 + col] = (__bf16)v;
        else
          ((float*)outv)[(size_t)(rbase + j) * 128 + col] = v;
      }
    }
}

// ---------------- aggregation: 16 lanes per node, 4 nodes/wave ----------------
__global__ __launch_bounds__(256) void k_agg(const __bf16* __restrict__ h,
                                             const int* __restrict__ rowptr,
                                             const int* __restrict__ csr,
                                             const float* __restrict__ dinv,
                                             __bf16* __restrict__ agg) {
  int t = threadIdx.x;
  int g = t >> 4;                    // 0..15 group in block
  int sl = t & 15;                   // lane in group; features sl*8..sl*8+7
  int nd = blockIdx.x * 16 + g;      // 2500 blocks * 16 == 40000
  float di = dinv[nd];
  float ns = di * di;                // self-loop norm AND 1/(deg+1)
  bf16x8 hv = *(const bf16x8*)&h[(size_t)nd * D + sl * 8];
  float sum[8], mn[8], mx[8];
  #pragma unroll
  for (int q = 0; q < 8; q++) {
    float v = (float)hv[q] * ns;
    sum[q] = v; mn[q] = v; mx[q] = v;
  }
  int e0 = rowptr[nd], e1 = rowptr[nd + 1];

  for (int eb = e0; eb < e1; eb += 16) {
    int rem = e1 - eb; if (rem > 16) rem = 16;
    int le = eb + (sl < rem ? sl : rem - 1);
    int re = csr[le];
    float nr = dinv[re] * di;

    int j = 0;
    for (; j + 4 <= rem; j += 4) {
      int r0 = __shfl(re, j + 0, 16), r1 = __shfl(re, j + 1, 16);
      int r2 = __shfl(re, j + 2, 16), r3 = __shfl(re, j + 3, 16);
      float n0 = __shfl(nr, j + 0, 16), n1 = __shfl(nr, j + 1, 16);
      float n2 = __shfl(nr, j + 2, 16), n3 = __shfl(nr, j + 3, 16);
      bf16x8 v0 = *(const bf16x8*)&h[(size_t)r0 * D + sl * 8];
      bf16x8 v1 = *(const bf16x8*)&h[(size_t)r1 * D + sl * 8];
      bf16x8 v2 = *(const bf16x8*)&h[(size_t)r2 * D + sl * 8];
      bf16x8 v3 = *(const bf16x8*)&h[(size_t)r3 * D + sl * 8];
      #pragma unroll
      for (int q = 0; q < 8; q++) {
        float a0 = (float)v0[q] * n0;
        sum[q] += a0; mn[q] = fminf(mn[q], a0); mx[q] = fmaxf(mx[q], a0);
        float a1 = (float)v1[q] * n1;
        sum[q] += a1; mn[q] = fminf(mn[q], a1); mx[q] = fmaxf(mx[q], a1);
        float a2 = (float)v2[q] * n2;
        sum[q] += a2; mn[q] = fminf(mn[q], a2); mx[q] = fmaxf(mx[q], a2);
        float a3 = (float)v3[q] * n3;
        sum[q] += a3; mn[q] = fminf(mn[q], a3); mx[q] = fmaxf(mx[q], a3);
      }
    }
    for (; j < rem; j++) {
      int r0 = __shfl(re, j, 16);
      float n0 = __shfl(nr, j, 16);
      bf16x8 v0 = *(const bf16x8*)&h[(size_t)r0 * D + sl * 8];
      #pragma unroll
      for (int q = 0; q < 8; q++) {
        float a0 = (float)v0[q] * n0;
        sum[q] += a0; mn[q] = fminf(mn[q], a0); mx[q] = fmaxf(mx[q], a0);
      }
    }
  }

  size_t base = (size_t)nd * FOUR_D + sl * 8;
  bf16x8 o;
  #pragma unroll
  for (int q = 0; q < 8; q++) o[q] = (__bf16)(sum[q] * ns);
  *(bf16x8*)&agg[base + 0] = o;
  #pragma unroll
  for (int q = 0; q < 8; q++) o[q] = (__bf16)sum[q];
  *(bf16x8*)&agg[base + 128] = o;
  #pragma unroll
  for (int q = 0; q < 8; q++) o[q] = (__bf16)mn[q];
  *(bf16x8*)&agg[base + 256] = o;
  #pragma unroll
  for (int q = 0; q < 8; q++) o[q] = (__bf16)mx[q];
  *(bf16x8*)&agg[base + 384] = o;
}

// ---------------- MFMA head + fused log_softmax ----------------
// logits = h[64-row tile][128] @ Wout[40][128]^T + b; out = log_softmax(logits)
// 4 waves; wave w handles rows w*16..w*16+15, 3 col-frags (48 cols, 40 valid).
__global__ __launch_bounds__(256) void k_head(const float* __restrict__ h,
                                              const __bf16* __restrict__ Whi,  // [40][128]
                                              const __bf16* __restrict__ Wlo,
                                              const float* __restrict__ bias,
                                              float* __restrict__ out) {
  __shared__ bf16x8 Ah[64 * 16], Al[64 * 16];   // 64 rows x 128 k
  __shared__ bf16x8 Bh[48 * 16], Bl[48 * 16];   // 48 rows (pad) x 128 k
  int t = threadIdx.x;
  int lane = t & 63, wid = t >> 6;
  int row0 = blockIdx.x * 64;                    // 625 * 64 == 40000

  // stage A: 1024 chunks
  #pragma unroll
  for (int c = 0; c < 4; c++) {
    int id = t + c * 256;
    int r = id >> 4, q = id & 15;
    const float* src = &h[(size_t)(row0 + r) * D + q * 8];
    float4 v0 = *(const float4*)src;
    float4 v1 = *(const float4*)(src + 4);
    float vv[8] = {v0.x, v0.y, v0.z, v0.w, v1.x, v1.y, v1.z, v1.w};
    bf16x8 hi, lo;
    #pragma unroll
    for (int j = 0; j < 8; j++) {
      __bf16 hh = (__bf16)vv[j];
      hi[j] = hh;
      lo[j] = (__bf16)(vv[j] - (float)hh);
    }
    int ch = r * 16 + (q ^ (r & 15));
    Ah[ch] = hi; Al[ch] = lo;
  }
  // stage B: 768 chunks (rows >= 40 zero)
  #pragma unroll
  for (int c = 0; c < 3; c++) {
    int id = t + c * 256;
    int r = id >> 4, q = id & 15;
    int ch = r * 16 + (q ^ (r & 15));
    bf16x8 hi = {}, lo = {};
    if (r < NCLS) {
      hi = *(const bf16x8*)&Whi[(size_t)r * D + q * 8];
      lo = *(const bf16x8*)&Wlo[(size_t)r * D + q * 8];
    }
    Bh[ch] = hi; Bl[ch] = lo;
  }
  __syncthreads();

  f32x4 acc[3];
  #pragma unroll
  for (int n = 0; n < 3; n++) acc[n] = (f32x4){0.f, 0.f, 0.f, 0.f};
  #pragma unroll
  for (int ks = 0; ks < 4; ks++) {
    int arow = wid * 16 + (lane & 15);
    int ach = arow * 16 + ((ks * 4 + (lane >> 4)) ^ (arow & 15));
    bf16x8 ah = Ah[ach], al = Al[ach];
    #pragma unroll
    for (int n = 0; n < 3; n++) {
      int brow = n * 16 + (lane & 15);
      int bch = brow * 16 + ((ks * 4 + (lane >> 4)) ^ (brow & 15));
      bf16x8 bh = Bh[bch], bl = Bl[bch];
      acc[n] = __builtin_amdgcn_mfma_f32_16x16x32_bf16(ah, bh, acc[n], 0, 0, 0);
      acc[n] = __builtin_amdgcn_mfma_f32_16x16x32_bf16(ah, bl, acc[n], 0, 0, 0);
      acc[n] = __builtin_amdgcn_mfma_f32_16x16x32_bf16(al, bh, acc[n], 0, 0, 0);
    }
  }

  // epilogue: per-row log_softmax. col = n*16 + (lane&15); row = (lane>>4)*4 + j
  int cl = lane & 15;
  float bb[3];
  #pragma unroll
  for (int n = 0; n < 3; n++) {
    int c = n * 16 + cl;
    bb[n] = (c < NCLS) ? bias[c] : 0.f;
  }
  #pragma unroll
  for (int j = 0; j < 4; j++) {
    float v[3];
    #pragma unroll
    for (int n = 0; n < 3; n++) {
      int c = n * 16 + cl;
      v[n] = (c < NCLS) ? acc[n][j] + bb[n] : -INFINITY;
    }
    float m = fmaxf(fmaxf(v[0], v[1]), v[2]);
    #pragma unroll
    for (int off = 1; off < 16; off <<= 1) m = fmaxf(m, __shfl_xor(m, off, 16));
    float s = 0.f;
    #pragma unroll
    for (int n = 0; n < 3; n++) {
      int c = n * 16 + cl;
      if (c < NCLS) s += expf(v[n] - m);
    }
    #pragma unroll
    for (int off = 1; off < 16; off <<= 1) s += __shfl_xor(s, off, 16);
    float ls = logf(s);
    int row = row0 + wid * 16 + (lane >> 4) * 4 + j;
    #pragma unroll
    for (int n = 0; n < 3; n++) {
      int c = n * 16 + cl;
      if (c < NCLS) out[(size_t)row * NCLS + c] = v[n] - m - ls;
    }
  }
}

// ---------------- launch ----------------
extern "C" void kernel_launch(void* const* d_in, const int* in_sizes, int n_in,
                              void* d_out, int out_size, void* d_ws, size_t ws_size,
                              hipStream_t stream) {
  const float* x    = (const float*)d_in[0];
  const int*   ei   = (const int*)  d_in[1];
  const float* W0   = (const float*)d_in[2];
  const float* C0   = (const float*)d_in[3];
  const float* b0   = (const float*)d_in[4];
  const float* W1   = (const float*)d_in[5];
  const float* C1   = (const float*)d_in[6];
  const float* b1   = (const float*)d_in[7];
  const float* Wout = (const float*)d_in[8];
  const float* bout = (const float*)d_in[9];
  float* out = (float*)d_out;

  char* ws = (char*)d_ws;
  size_t o = 0;
  auto take = [&](size_t bytes) -> char* {
    char* p = ws + o;
    o += (bytes + 255) & ~(size_t)255;
    return p;
  };
  int*    deg    = (int*)   take((size_t)NN * 4);
  int*    rowptr = (int*)   take((size_t)(NN + 1) * 4);
  int*    cursor = (int*)   take((size_t)NN * 4);
  int*    bsum   = (int*)   take(64 * 4);
  int*    csr    = (int*)   take((size_t)NE * 4);
  float*  dinv   = (float*) take((size_t)NN * 4);
  __bf16* Whi0   = (__bf16*)take(128 * 128 * 2);
  __bf16* Wlo0   = (__bf16*)take(128 * 128 * 2);
  __bf16* Chi0   = (__bf16*)take(128 * 512 * 2);
  __bf16* Clo0   = (__bf16*)take(128 * 512 * 2);
  __bf16* Whi1   = (__bf16*)take(128 * 128 * 2);
  __bf16* Wlo1   = (__bf16*)take(128 * 128 * 2);
  __bf16* Chi1   = (__bf16*)take(128 * 512 * 2);
  __bf16* Clo1   = (__bf16*)take(128 * 512 * 2);
  __bf16* Ohi    = (__bf16*)take(40 * 128 * 2);
  __bf16* Olo    = (__bf16*)take(40 * 128 * 2);
  __bf16* bufA   = (__bf16*)take((size_t)NN * 128 * 2);   // h, bf16
  __bf16* bufB   = (__bf16*)take((size_t)NN * 512 * 2);   // agg, bf16
  float*  bufC   = (float*) take((size_t)NN * 128 * 4);   // layer out, fp32

  const int* row = ei;        // edge_index[0]
  const int* col = ei + NE;   // edge_index[1]

  // CSR by destination
  k_zero_int<<<cdiv(NN, 256), 256, 0, stream>>>(deg, NN);
  k_count<<<cdiv(NE, 256), 256, 0, stream>>>(col, deg);
  k_scan1<<<40, 256, 0, stream>>>(deg, rowptr, bsum);
  k_scan2<<<1, 64, 0, stream>>>(bsum, 40, rowptr + NN);
  k_scan3<<<cdiv(NN, 256), 256, 0, stream>>>(rowptr, bsum, deg, cursor, dinv);
  k_fill<<<cdiv(NE, 256), 256, 0, stream>>>(row, col, cursor, csr);

  // weight prep: one dispatch for all 5 splits
  k_splitall<<<cdiv(168960, 256), 256, 0, stream>>>(W0, Whi0, Wlo0, C0, Chi0, Clo0,
                                                    W1, Whi1, Wlo1, C1, Chi1, Clo1,
                                                    Wout, Ohi, Olo);

  // layer 0: lin (fp32 A -> bf16 h), agg (bf16), combine (bf16 A -> fp32)
  k_mm<128, false, true, false, false><<<625, 256, 0, stream>>>(x, Whi0, Wlo0, nullptr, bufA);
  k_agg<<<2500, 256, 0, stream>>>(bufA, rowptr, csr, dinv, bufB);
  k_mm<512, true, false, true, true><<<625, 256, 0, stream>>>(bufB, Chi0, Clo0, b0, bufC);
  // layer 1
  k_mm<128, false, true, false, false><<<625, 256, 0, stream>>>(bufC, Whi1, Wlo1, nullptr, bufA);
  k_agg<<<2500, 256, 0, stream>>>(bufA, rowptr, csr, dinv, bufB);
  k_mm<512, true, false, true, true><<<625, 256, 0, stream>>>(bufB, Chi1, Clo1, b1, bufC);
  // head + log_softmax (MFMA)
  k_head<<<625, 256, 0, stream>>>(bufC, Ohi, Olo, bout, out);
}

// Round 6
// 195.741 us; speedup vs baseline: 2.5303x; 1.0782x over previous
//
#include <hip/hip_runtime.h>
#include <hip/hip_bf16.h>
#include <math.h>

#define NN 40000
#define NE 640000
#define D 128
#define NCLS 40
#define FOUR_D 512

typedef __bf16 bf16x8 __attribute__((ext_vector_type(8)));
typedef float  f32x4  __attribute__((ext_vector_type(4)));

static inline int cdiv(int a, int b){ return (a + b - 1) / b; }

// ---------------- setup kernels ----------------

// fused: zero deg + split all 5 weight tensors fp32 -> bf16 hi/lo
// split sizes: W0 16384, C0 65536, W1 16384, C1 65536, Wout 5120 (total 168960)
__global__ __launch_bounds__(256) void k_prep(int* __restrict__ deg,
                                              const float* __restrict__ W0, __bf16* h0, __bf16* l0,
                                              const float* __restrict__ C0, __bf16* h1, __bf16* l1,
                                              const float* __restrict__ W1, __bf16* h2, __bf16* l2,
                                              const float* __restrict__ C1, __bf16* h3, __bf16* l3,
                                              const float* __restrict__ WO, __bf16* h4, __bf16* l4) {
  int i = blockIdx.x * 256 + threadIdx.x;
  if (i < NN) deg[i] = 0;
  const float* src; __bf16* dh; __bf16* dl; int off;
  if      (i < 16384)  { src = W0; dh = h0; dl = l0; off = i; }
  else if (i < 81920)  { src = C0; dh = h1; dl = l1; off = i - 16384; }
  else if (i < 98304)  { src = W1; dh = h2; dl = l2; off = i - 81920; }
  else if (i < 163840) { src = C1; dh = h3; dl = l3; off = i - 98304; }
  else if (i < 168960) { src = WO; dh = h4; dl = l4; off = i - 163840; }
  else return;
  float v = src[off];
  __bf16 h = (__bf16)v;
  dh[off] = h;
  dl[off] = (__bf16)(v - (float)h);
}

__global__ __launch_bounds__(256) void k_count(const int* __restrict__ col,
                                               int* __restrict__ deg) {
  int i = blockIdx.x * 256 + threadIdx.x;
  if (i < NE) atomicAdd(&deg[col[i]], 1);
}

__global__ __launch_bounds__(256) void k_scan1(const int* __restrict__ cnt,
                                               int* __restrict__ excl,
                                               int* __restrict__ bsum) {
  __shared__ int sh[256];
  int b = blockIdx.x, t = threadIdx.x;
  int base = b * 1024 + t * 4;
  int v0 = (base + 0 < NN) ? cnt[base + 0] : 0;
  int v1 = (base + 1 < NN) ? cnt[base + 1] : 0;
  int v2 = (base + 2 < NN) ? cnt[base + 2] : 0;
  int v3 = (base + 3 < NN) ? cnt[base + 3] : 0;
  sh[t] = v0 + v1 + v2 + v3;
  __syncthreads();
  for (int off = 1; off < 256; off <<= 1) {
    int x = (t >= off) ? sh[t - off] : 0;
    __syncthreads();
    sh[t] += x;
    __syncthreads();
  }
  int pre = (t > 0) ? sh[t - 1] : 0;
  if (base + 0 < NN) excl[base + 0] = pre;  pre += v0;
  if (base + 1 < NN) excl[base + 1] = pre;  pre += v1;
  if (base + 2 < NN) excl[base + 2] = pre;  pre += v2;
  if (base + 3 < NN) excl[base + 3] = pre;
  if (t == 255) bsum[b] = sh[255];
}

__global__ void k_scan2(int* __restrict__ bsum, int nb, int* __restrict__ total_out) {
  int t = threadIdx.x;  // 64 threads
  __shared__ int sh[64];
  sh[t] = (t < nb) ? bsum[t] : 0;
  __syncthreads();
  if (t == 0) {
    int run = 0;
    for (int i = 0; i < nb; i++) { int v = sh[i]; sh[i] = run; run += v; }
    *total_out = run;
  }
  __syncthreads();
  if (t < nb) bsum[t] = sh[t];
}

__global__ __launch_bounds__(256) void k_scan3(int* __restrict__ rowptr,
                                               const int* __restrict__ bsum,
                                               const int* __restrict__ deg,
                                               int* __restrict__ cursor,
                                               float* __restrict__ dinv) {
  int i = blockIdx.x * 256 + threadIdx.x;
  if (i < NN) {
    int v = rowptr[i] + bsum[i >> 10];
    rowptr[i] = v;
    cursor[i] = v;
    dinv[i] = rsqrtf((float)(deg[i] + 1));
  }
}

__global__ __launch_bounds__(256) void k_fill(const int* __restrict__ row,
                                              const int* __restrict__ col,
                                              int* __restrict__ cursor,
                                              int* __restrict__ csr) {
  int i = blockIdx.x * 256 + threadIdx.x;
  if (i < NE) {
    int c = col[i];
    int p = atomicAdd(&cursor[c], 1);
    csr[p] = row[i];
  }
}

// ---------------- MFMA GEMM: out[m][n] = sum_k A[m][k] * W[n][k] ----------------
// AFP32: A fp32, converted to single bf16 in staging; else A bf16 copy.
// BLO: use hi+lo weights (2 MFMAs) else hi only (1 MFMA). Output always bf16.
template<int K, bool AFP32, bool BLO, bool RELU, bool HASBIAS>
__global__ __launch_bounds__(256) void k_mm(const void* __restrict__ Av,
                                            const __bf16* __restrict__ BhG,
                                            const __bf16* __restrict__ BlG,
                                            const float* __restrict__ bias,
                                            __bf16* __restrict__ out) {
  __shared__ bf16x8 Ah[64 * 8];
  __shared__ bf16x8 Bh[128 * 8];
  __shared__ bf16x8 Bl[BLO ? 128 * 8 : 8];
  int t = threadIdx.x;
  int lane = t & 63, wid = t >> 6;
  int wr = wid >> 1, wc = wid & 1;
  int row0 = blockIdx.x * 64;            // 625 * 64 == 40000

  f32x4 acc[2][4];
  #pragma unroll
  for (int m = 0; m < 2; m++)
    #pragma unroll
    for (int n = 0; n < 4; n++) acc[m][n] = (f32x4){0.f, 0.f, 0.f, 0.f};

  for (int k0 = 0; k0 < K; k0 += 64) {
    __syncthreads();
    // stage A: 64 rows x 64 k
    #pragma unroll
    for (int c = 0; c < 2; c++) {
      int id = t + c * 256;              // 0..511
      int r = id >> 3, q = id & 7;
      int ch = r * 8 + (q ^ (r & 7));
      if constexpr (AFP32) {
        const float* A = (const float*)Av;
        const float* src = &A[(size_t)(row0 + r) * K + k0 + q * 8];
        float4 v0 = *(const float4*)src;
        float4 v1 = *(const float4*)(src + 4);
        float vv[8] = {v0.x, v0.y, v0.z, v0.w, v1.x, v1.y, v1.z, v1.w};
        bf16x8 hi;
        #pragma unroll
        for (int j = 0; j < 8; j++) hi[j] = (__bf16)vv[j];
        Ah[ch] = hi;
      } else {
        const __bf16* A = (const __bf16*)Av;
        Ah[ch] = *(const bf16x8*)&A[(size_t)(row0 + r) * K + k0 + q * 8];
      }
    }
    // stage B: 128 rows x 64 k
    #pragma unroll
    for (int c = 0; c < 4; c++) {
      int id = t + c * 256;              // 0..1023
      int r = id >> 3, q = id & 7;
      int ch = r * 8 + (q ^ (r & 7));
      Bh[ch] = *(const bf16x8*)&BhG[(size_t)r * K + k0 + q * 8];
      if constexpr (BLO)
        Bl[ch] = *(const bf16x8*)&BlG[(size_t)r * K + k0 + q * 8];
    }
    __syncthreads();
    #pragma unroll
    for (int ks = 0; ks < 2; ks++) {
      bf16x8 ah[2], bh[4], bl[4];
      #pragma unroll
      for (int m = 0; m < 2; m++) {
        int row = wr * 32 + m * 16 + (lane & 15);
        int ch = row * 8 + ((ks * 4 + (lane >> 4)) ^ (row & 7));
        ah[m] = Ah[ch];
      }
      #pragma unroll
      for (int n = 0; n < 4; n++) {
        int row = wc * 64 + n * 16 + (lane & 15);
        int ch = row * 8 + ((ks * 4 + (lane >> 4)) ^ (row & 7));
        bh[n] = Bh[ch];
        if constexpr (BLO) bl[n] = Bl[ch];
      }
      #pragma unroll
      for (int m = 0; m < 2; m++)
        #pragma unroll
        for (int n = 0; n < 4; n++) {
          acc[m][n] = __builtin_amdgcn_mfma_f32_16x16x32_bf16(ah[m], bh[n], acc[m][n], 0, 0, 0);
          if constexpr (BLO)
            acc[m][n] = __builtin_amdgcn_mfma_f32_16x16x32_bf16(ah[m], bl[n], acc[m][n], 0, 0, 0);
        }
    }
  }

  // epilogue: C/D layout col = lane&15, row = (lane>>4)*4 + j
  #pragma unroll
  for (int m = 0; m < 2; m++)
    #pragma unroll
    for (int n = 0; n < 4; n++) {
      int col = wc * 64 + n * 16 + (lane & 15);
      int rbase = row0 + wr * 32 + m * 16 + (lane >> 4) * 4;
      float bv = HASBIAS ? bias[col] : 0.f;
      #pragma unroll
      for (int j = 0; j < 4; j++) {
        float v = acc[m][n][j] + bv;
        if (RELU) v = fmaxf(v, 0.f);
        out[(size_t)(rbase + j) * 128 + col] = (__bf16)v;
      }
    }
}

// ---------------- aggregation: 16 lanes per node, 8 gathers in flight ----------------
__global__ __launch_bounds__(256) void k_agg(const __bf16* __restrict__ h,
                                             const int* __restrict__ rowptr,
                                             const int* __restrict__ csr,
                                             const float* __restrict__ dinv,
                                             __bf16* __restrict__ agg) {
  int t = threadIdx.x;
  int g = t >> 4;                    // 0..15 group in block
  int sl = t & 15;                   // lane in group; features sl*8..sl*8+7
  int nd = blockIdx.x * 16 + g;      // 2500 blocks * 16 == 40000
  float di = dinv[nd];
  float ns = di * di;                // self-loop norm AND 1/(deg+1)
  bf16x8 hv = *(const bf16x8*)&h[(size_t)nd * D + sl * 8];
  float sum[8], mn[8], mx[8];
  #pragma unroll
  for (int q = 0; q < 8; q++) {
    float v = (float)hv[q] * ns;
    sum[q] = v; mn[q] = v; mx[q] = v;
  }
  int e0 = rowptr[nd], e1 = rowptr[nd + 1];

  for (int eb = e0; eb < e1; eb += 16) {
    int rem = e1 - eb; if (rem > 16) rem = 16;
    int le = eb + (sl < rem ? sl : rem - 1);
    int re = csr[le];                  // lane sl holds edge sl's source
    float nr = dinv[re] * di;          // lane sl holds edge sl's norm

    int j = 0;
    for (; j + 8 <= rem; j += 8) {
      int   r[8]; float nn[8]; bf16x8 v[8];
      #pragma unroll
      for (int u = 0; u < 8; u++) {
        r[u]  = __shfl(re, j + u, 16);
        nn[u] = __shfl(nr, j + u, 16);
      }
      #pragma unroll
      for (int u = 0; u < 8; u++)
        v[u] = *(const bf16x8*)&h[(size_t)r[u] * D + sl * 8];
      #pragma unroll
      for (int u = 0; u < 8; u++)
        #pragma unroll
        for (int q = 0; q < 8; q++) {
          float a = (float)v[u][q] * nn[u];
          sum[q] += a; mn[q] = fminf(mn[q], a); mx[q] = fmaxf(mx[q], a);
        }
    }
    for (; j + 4 <= rem; j += 4) {
      int   r[4]; float nn[4]; bf16x8 v[4];
      #pragma unroll
      for (int u = 0; u < 4; u++) {
        r[u]  = __shfl(re, j + u, 16);
        nn[u] = __shfl(nr, j + u, 16);
      }
      #pragma unroll
      for (int u = 0; u < 4; u++)
        v[u] = *(const bf16x8*)&h[(size_t)r[u] * D + sl * 8];
      #pragma unroll
      for (int u = 0; u < 4; u++)
        #pragma unroll
        for (int q = 0; q < 8; q++) {
          float a = (float)v[u][q] * nn[u];
          sum[q] += a; mn[q] = fminf(mn[q], a); mx[q] = fmaxf(mx[q], a);
        }
    }
    for (; j < rem; j++) {
      int r0 = __shfl(re, j, 16);
      float n0 = __shfl(nr, j, 16);
      bf16x8 v0 = *(const bf16x8*)&h[(size_t)r0 * D + sl * 8];
      #pragma unroll
      for (int q = 0; q < 8; q++) {
        float a0 = (float)v0[q] * n0;
        sum[q] += a0; mn[q] = fminf(mn[q], a0); mx[q] = fmaxf(mx[q], a0);
      }
    }
  }

  size_t base = (size_t)nd * FOUR_D + sl * 8;
  bf16x8 o;
  #pragma unroll
  for (int q = 0; q < 8; q++) o[q] = (__bf16)(sum[q] * ns);
  *(bf16x8*)&agg[base + 0] = o;
  #pragma unroll
  for (int q = 0; q < 8; q++) o[q] = (__bf16)sum[q];
  *(bf16x8*)&agg[base + 128] = o;
  #pragma unroll
  for (int q = 0; q < 8; q++) o[q] = (__bf16)mn[q];
  *(bf16x8*)&agg[base + 256] = o;
  #pragma unroll
  for (int q = 0; q < 8; q++) o[q] = (__bf16)mx[q];
  *(bf16x8*)&agg[base + 384] = o;
}

// ---------------- MFMA head + fused log_softmax ----------------
// logits = h[64-row tile][128](bf16) @ Wout[40][128]^T + b; out = log_softmax
__global__ __launch_bounds__(256) void k_head(const __bf16* __restrict__ h,
                                              const __bf16* __restrict__ Whi,  // [40][128]
                                              const __bf16* __restrict__ Wlo,
                                              const float* __restrict__ bias,
                                              float* __restrict__ out) {
  __shared__ bf16x8 Ah[64 * 16];                // 64 rows x 128 k
  __shared__ bf16x8 Bh[48 * 16], Bl[48 * 16];   // 48 rows (pad) x 128 k
  int t = threadIdx.x;
  int lane = t & 63, wid = t >> 6;
  int row0 = blockIdx.x * 64;                    // 625 * 64 == 40000

  // stage A: 1024 chunks (bf16 copy)
  #pragma unroll
  for (int c = 0; c < 4; c++) {
    int id = t + c * 256;
    int r = id >> 4, q = id & 15;
    int ch = r * 16 + (q ^ (r & 15));
    Ah[ch] = *(const bf16x8*)&h[(size_t)(row0 + r) * D + q * 8];
  }
  // stage B: 768 chunks (rows >= 40 zero)
  #pragma unroll
  for (int c = 0; c < 3; c++) {
    int id = t + c * 256;
    int r = id >> 4, q = id & 15;
    int ch = r * 16 + (q ^ (r & 15));
    bf16x8 hi = {}, lo = {};
    if (r < NCLS) {
      hi = *(const bf16x8*)&Whi[(size_t)r * D + q * 8];
      lo = *(const bf16x8*)&Wlo[(size_t)r * D + q * 8];
    }
    Bh[ch] = hi; Bl[ch] = lo;
  }
  __syncthreads();

  f32x4 acc[3];
  #pragma unroll
  for (int n = 0; n < 3; n++) acc[n] = (f32x4){0.f, 0.f, 0.f, 0.f};
  #pragma unroll
  for (int ks = 0; ks < 4; ks++) {
    int arow = wid * 16 + (lane & 15);
    int ach = arow * 16 + ((ks * 4 + (lane >> 4)) ^ (arow & 15));
    bf16x8 ah = Ah[ach];
    #pragma unroll
    for (int n = 0; n < 3; n++) {
      int brow = n * 16 + (lane & 15);
      int bch = brow * 16 + ((ks * 4 + (lane >> 4)) ^ (brow & 15));
      bf16x8 bh = Bh[bch], bl = Bl[bch];
      acc[n] = __builtin_amdgcn_mfma_f32_16x16x32_bf16(ah, bh, acc[n], 0, 0, 0);
      acc[n] = __builtin_amdgcn_mfma_f32_16x16x32_bf16(ah, bl, acc[n], 0, 0, 0);
    }
  }

  // per-row log_softmax. col = n*16 + (lane&15); row = (lane>>4)*4 + j
  int cl = lane & 15;
  float bb[3];
  #pragma unroll
  for (int n = 0; n < 3; n++) {
    int c = n * 16 + cl;
    bb[n] = (c < NCLS) ? bias[c] : 0.f;
  }
  #pragma unroll
  for (int j = 0; j < 4; j++) {
    float v[3];
    #pragma unroll
    for (int n = 0; n < 3; n++) {
      int c = n * 16 + cl;
      v[n] = (c < NCLS) ? acc[n][j] + bb[n] : -INFINITY;
    }
    float m = fmaxf(fmaxf(v[0], v[1]), v[2]);
    #pragma unroll
    for (int off = 1; off < 16; off <<= 1) m = fmaxf(m, __shfl_xor(m, off, 16));
    float s = 0.f;
    #pragma unroll
    for (int n = 0; n < 3; n++) {
      int c = n * 16 + cl;
      if (c < NCLS) s += expf(v[n] - m);
    }
    #pragma unroll
    for (int off = 1; off < 16; off <<= 1) s += __shfl_xor(s, off, 16);
    float ls = logf(s);
    int row = row0 + wid * 16 + (lane >> 4) * 4 + j;
    #pragma unroll
    for (int n = 0; n < 3; n++) {
      int c = n * 16 + cl;
      if (c < NCLS) out[(size_t)row * NCLS + c] = v[n] - m - ls;
    }
  }
}

// ---------------- launch ----------------
extern "C" void kernel_launch(void* const* d_in, const int* in_sizes, int n_in,
                              void* d_out, int out_size, void* d_ws, size_t ws_size,
                              hipStream_t stream) {
  const float* x    = (const float*)d_in[0];
  const int*   ei   = (const int*)  d_in[1];
  const float* W0   = (const float*)d_in[2];
  const float* C0   = (const float*)d_in[3];
  const float* b0   = (const float*)d_in[4];
  const float* W1   = (const float*)d_in[5];
  const float* C1   = (const float*)d_in[6];
  const float* b1   = (const float*)d_in[7];
  const float* Wout = (const float*)d_in[8];
  const float* bout = (const float*)d_in[9];
  float* out = (float*)d_out;

  char* ws = (char*)d_ws;
  size_t o = 0;
  auto take = [&](size_t bytes) -> char* {
    char* p = ws + o;
    o += (bytes + 255) & ~(size_t)255;
    return p;
  };
  int*    deg    = (int*)   take((size_t)NN * 4);
  int*    rowptr = (int*)   take((size_t)(NN + 1) * 4);
  int*    cursor = (int*)   take((size_t)NN * 4);
  int*    bsum   = (int*)   take(64 * 4);
  int*    csr    = (int*)   take((size_t)NE * 4);
  float*  dinv   = (float*) take((size_t)NN * 4);
  __bf16* Whi0   = (__bf16*)take(128 * 128 * 2);
  __bf16* Wlo0   = (__bf16*)take(128 * 128 * 2);
  __bf16* Chi0   = (__bf16*)take(128 * 512 * 2);
  __bf16* Clo0   = (__bf16*)take(128 * 512 * 2);
  __bf16* Whi1   = (__bf16*)take(128 * 128 * 2);
  __bf16* Wlo1   = (__bf16*)take(128 * 128 * 2);
  __bf16* Chi1   = (__bf16*)take(128 * 512 * 2);
  __bf16* Clo1   = (__bf16*)take(128 * 512 * 2);
  __bf16* Ohi    = (__bf16*)take(40 * 128 * 2);
  __bf16* Olo    = (__bf16*)take(40 * 128 * 2);
  __bf16* bufA   = (__bf16*)take((size_t)NN * 128 * 2);   // h, bf16
  __bf16* bufB   = (__bf16*)take((size_t)NN * 512 * 2);   // agg, bf16
  __bf16* bufC   = (__bf16*)take((size_t)NN * 128 * 2);   // layer out, bf16

  const int* row = ei;        // edge_index[0]
  const int* col = ei + NE;   // edge_index[1]

  // fused zero + weight split
  k_prep<<<cdiv(168960, 256), 256, 0, stream>>>(deg,
                                                W0, Whi0, Wlo0, C0, Chi0, Clo0,
                                                W1, Whi1, Wlo1, C1, Chi1, Clo1,
                                                Wout, Ohi, Olo);
  // CSR by destination
  k_count<<<cdiv(NE, 256), 256, 0, stream>>>(col, deg);
  k_scan1<<<40, 256, 0, stream>>>(deg, rowptr, bsum);
  k_scan2<<<1, 64, 0, stream>>>(bsum, 40, rowptr + NN);
  k_scan3<<<cdiv(NN, 256), 256, 0, stream>>>(rowptr, bsum, deg, cursor, dinv);
  k_fill<<<cdiv(NE, 256), 256, 0, stream>>>(row, col, cursor, csr);

  // layer 0: lin (fp32 x, W hi/lo), agg, combine (C hi only)
  k_mm<128, true,  true,  false, false><<<625, 256, 0, stream>>>(x,    Whi0, Wlo0, nullptr, bufA);
  k_agg<<<2500, 256, 0, stream>>>(bufA, rowptr, csr, dinv, bufB);
  k_mm<512, false, false, true,  true ><<<625, 256, 0, stream>>>(bufB, Chi0, nullptr, b0, bufC);
  // layer 1: lin (bf16 A, W hi/lo)
  k_mm<128, false, true,  false, false><<<625, 256, 0, stream>>>(bufC, Whi1, Wlo1, nullptr, bufA);
  k_agg<<<2500, 256, 0, stream>>>(bufA, rowptr, csr, dinv, bufB);
  k_mm<512, false, false, true,  true ><<<625, 256, 0, stream>>>(bufB, Chi1, nullptr, b1, bufC);
  // head + log_softmax (MFMA)
  k_head<<<625, 256, 0, stream>>>(bufC, Ohi, Olo, bout, out);
}

// Round 7
// 187.285 us; speedup vs baseline: 2.6445x; 1.0452x over previous
//
#include <hip/hip_runtime.h>
#include <hip/hip_bf16.h>
#include <math.h>

#define NN 40000
#define NE 640000
#define D 128
#define NCLS 40

typedef __bf16 bf16x8 __attribute__((ext_vector_type(8)));
typedef float  f32x4  __attribute__((ext_vector_type(4)));

static inline int cdiv(int a, int b){ return (a + b - 1) / b; }

// ---------------- setup kernels ----------------

// fused: zero deg + split all 5 weight tensors fp32 -> bf16 hi/lo
__global__ __launch_bounds__(256) void k_prep(int* __restrict__ deg,
                                              const float* __restrict__ W0, __bf16* h0, __bf16* l0,
                                              const float* __restrict__ C0, __bf16* h1, __bf16* l1,
                                              const float* __restrict__ W1, __bf16* h2, __bf16* l2,
                                              const float* __restrict__ C1, __bf16* h3, __bf16* l3,
                                              const float* __restrict__ WO, __bf16* h4, __bf16* l4) {
  int i = blockIdx.x * 256 + threadIdx.x;
  if (i < NN) deg[i] = 0;
  const float* src; __bf16* dh; __bf16* dl; int off;
  if      (i < 16384)  { src = W0; dh = h0; dl = l0; off = i; }
  else if (i < 81920)  { src = C0; dh = h1; dl = l1; off = i - 16384; }
  else if (i < 98304)  { src = W1; dh = h2; dl = l2; off = i - 81920; }
  else if (i < 163840) { src = C1; dh = h3; dl = l3; off = i - 98304; }
  else if (i < 168960) { src = WO; dh = h4; dl = l4; off = i - 163840; }
  else return;
  float v = src[off];
  __bf16 h = (__bf16)v;
  dh[off] = h;
  dl[off] = (__bf16)(v - (float)h);
}

__global__ __launch_bounds__(256) void k_count(const int* __restrict__ col,
                                               int* __restrict__ deg) {
  int i = blockIdx.x * 256 + threadIdx.x;
  if (i < NE) atomicAdd(&deg[col[i]], 1);
}

__global__ __launch_bounds__(256) void k_scan1(const int* __restrict__ cnt,
                                               int* __restrict__ excl,
                                               int* __restrict__ bsum) {
  __shared__ int sh[256];
  int b = blockIdx.x, t = threadIdx.x;
  int base = b * 1024 + t * 4;
  int v0 = (base + 0 < NN) ? cnt[base + 0] : 0;
  int v1 = (base + 1 < NN) ? cnt[base + 1] : 0;
  int v2 = (base + 2 < NN) ? cnt[base + 2] : 0;
  int v3 = (base + 3 < NN) ? cnt[base + 3] : 0;
  sh[t] = v0 + v1 + v2 + v3;
  __syncthreads();
  for (int off = 1; off < 256; off <<= 1) {
    int x = (t >= off) ? sh[t - off] : 0;
    __syncthreads();
    sh[t] += x;
    __syncthreads();
  }
  int pre = (t > 0) ? sh[t - 1] : 0;
  if (base + 0 < NN) excl[base + 0] = pre;  pre += v0;
  if (base + 1 < NN) excl[base + 1] = pre;  pre += v1;
  if (base + 2 < NN) excl[base + 2] = pre;  pre += v2;
  if (base + 3 < NN) excl[base + 3] = pre;
  if (t == 255) bsum[b] = sh[255];
}

__global__ void k_scan2(int* __restrict__ bsum, int nb, int* __restrict__ total_out) {
  int t = threadIdx.x;  // 64 threads
  __shared__ int sh[64];
  sh[t] = (t < nb) ? bsum[t] : 0;
  __syncthreads();
  if (t == 0) {
    int run = 0;
    for (int i = 0; i < nb; i++) { int v = sh[i]; sh[i] = run; run += v; }
    *total_out = run;
  }
  __syncthreads();
  if (t < nb) bsum[t] = sh[t];
}

__global__ __launch_bounds__(256) void k_scan3(int* __restrict__ rowptr,
                                               const int* __restrict__ bsum,
                                               const int* __restrict__ deg,
                                               int* __restrict__ cursor,
                                               float* __restrict__ dinv) {
  int i = blockIdx.x * 256 + threadIdx.x;
  if (i < NN) {
    int v = rowptr[i] + bsum[i >> 10];
    rowptr[i] = v;
    cursor[i] = v;
    dinv[i] = rsqrtf((float)(deg[i] + 1));
  }
}

__global__ __launch_bounds__(256) void k_fill(const int* __restrict__ row,
                                              const int* __restrict__ col,
                                              int* __restrict__ cursor,
                                              int* __restrict__ csr) {
  int i = blockIdx.x * 256 + threadIdx.x;
  if (i < NE) {
    int c = col[i];
    int p = atomicAdd(&cursor[c], 1);
    csr[p] = row[i];
  }
}

// ---------------- lin GEMM: hs[m][n] = dinv[m] * sum_k A[m][k] * W[n][k] ----------------
// K = 128. A fp32 (AFP32) or bf16. W hi+lo (2 MFMAs). Output bf16, row-scaled by dinv.
template<bool AFP32>
__global__ __launch_bounds__(256) void k_lin(const void* __restrict__ Av,
                                             const __bf16* __restrict__ BhG,
                                             const __bf16* __restrict__ BlG,
                                             const float* __restrict__ rowscale,
                                             __bf16* __restrict__ out) {
  __shared__ bf16x8 Ah[64 * 8];
  __shared__ bf16x8 Bh[128 * 8], Bl[128 * 8];
  int t = threadIdx.x;
  int lane = t & 63, wid = t >> 6;
  int wr = wid >> 1, wc = wid & 1;
  int row0 = blockIdx.x * 64;            // 625 * 64 == 40000

  f32x4 acc[2][4];
  #pragma unroll
  for (int m = 0; m < 2; m++)
    #pragma unroll
    for (int n = 0; n < 4; n++) acc[m][n] = (f32x4){0.f, 0.f, 0.f, 0.f};

  for (int k0 = 0; k0 < 128; k0 += 64) {
    __syncthreads();
    // stage A: 64 rows x 64 k
    #pragma unroll
    for (int c = 0; c < 2; c++) {
      int id = t + c * 256;              // 0..511
      int r = id >> 3, q = id & 7;
      int ch = r * 8 + (q ^ (r & 7));
      if constexpr (AFP32) {
        const float* A = (const float*)Av;
        const float* src = &A[(size_t)(row0 + r) * 128 + k0 + q * 8];
        float4 v0 = *(const float4*)src;
        float4 v1 = *(const float4*)(src + 4);
        float vv[8] = {v0.x, v0.y, v0.z, v0.w, v1.x, v1.y, v1.z, v1.w};
        bf16x8 hi;
        #pragma unroll
        for (int j = 0; j < 8; j++) hi[j] = (__bf16)vv[j];
        Ah[ch] = hi;
      } else {
        const __bf16* A = (const __bf16*)Av;
        Ah[ch] = *(const bf16x8*)&A[(size_t)(row0 + r) * 128 + k0 + q * 8];
      }
    }
    // stage B: 128 rows x 64 k (hi and lo)
    #pragma unroll
    for (int c = 0; c < 4; c++) {
      int id = t + c * 256;              // 0..1023
      int r = id >> 3, q = id & 7;
      int ch = r * 8 + (q ^ (r & 7));
      Bh[ch] = *(const bf16x8*)&BhG[(size_t)r * 128 + k0 + q * 8];
      Bl[ch] = *(const bf16x8*)&BlG[(size_t)r * 128 + k0 + q * 8];
    }
    __syncthreads();
    #pragma unroll
    for (int ks = 0; ks < 2; ks++) {
      bf16x8 ah[2], bh[4], bl[4];
      #pragma unroll
      for (int m = 0; m < 2; m++) {
        int row = wr * 32 + m * 16 + (lane & 15);
        int ch = row * 8 + ((ks * 4 + (lane >> 4)) ^ (row & 7));
        ah[m] = Ah[ch];
      }
      #pragma unroll
      for (int n = 0; n < 4; n++) {
        int row = wc * 64 + n * 16 + (lane & 15);
        int ch = row * 8 + ((ks * 4 + (lane >> 4)) ^ (row & 7));
        bh[n] = Bh[ch]; bl[n] = Bl[ch];
      }
      #pragma unroll
      for (int m = 0; m < 2; m++)
        #pragma unroll
        for (int n = 0; n < 4; n++) {
          acc[m][n] = __builtin_amdgcn_mfma_f32_16x16x32_bf16(ah[m], bh[n], acc[m][n], 0, 0, 0);
          acc[m][n] = __builtin_amdgcn_mfma_f32_16x16x32_bf16(ah[m], bl[n], acc[m][n], 0, 0, 0);
        }
    }
  }

  // epilogue: hs = dinv[row] * h  (row scale folded in; C/D: col=lane&15, row=(lane>>4)*4+j)
  #pragma unroll
  for (int m = 0; m < 2; m++) {
    int rbase = row0 + wr * 32 + m * 16 + (lane >> 4) * 4;
    float rs[4];
    #pragma unroll
    for (int j = 0; j < 4; j++) rs[j] = rowscale[rbase + j];
    #pragma unroll
    for (int n = 0; n < 4; n++) {
      int col = wc * 64 + n * 16 + (lane & 15);
      #pragma unroll
      for (int j = 0; j < 4; j++)
        out[(size_t)(rbase + j) * 128 + col] = (__bf16)(acc[m][n][j] * rs[j]);
    }
  }
}

// ---------------- fused aggregate + combine GEMM + bias + ReLU ----------------
// Per block: 32 nodes. Phase 1: gather hs rows (pre-scaled by dinv[src]), reduce
// sum/min/max unscaled, finalize [mean|add|min|max]*di into LDS As (bf16,
// swizzled chunks). Phase 2: out[32][128] = As[32][512] @ C[128][512]^T + b, ReLU.
__global__ __launch_bounds__(256) void k_aggcomb(const __bf16* __restrict__ hs,
                                                 const int* __restrict__ rowptr,
                                                 const int* __restrict__ csr,
                                                 const float* __restrict__ dinv,
                                                 const __bf16* __restrict__ CW,   // [128][512] hi
                                                 const float* __restrict__ bias,
                                                 __bf16* __restrict__ out) {
  __shared__ bf16x8 As[32 * 64];   // 32 rows x 512 k; chunk = r*64 + (qq ^ (r&7))
  __shared__ bf16x8 Bs[128 * 8];   // 128 cols x 64 k per K-tile
  int t = threadIdx.x;
  int lane = t & 63, wid = t >> 6;
  int g = t >> 4;                  // 16 groups of 16 lanes
  int sl = t & 15;                 // features sl*8 .. sl*8+7
  int nd0 = blockIdx.x * 32;       // 1250 blocks * 32 == 40000

  // ---- phase 1: aggregation (group g does local rows g and g+16) ----
  #pragma unroll
  for (int rep = 0; rep < 2; rep++) {
    int lr = g + rep * 16;
    int nd = nd0 + lr;
    float di = dinv[nd];
    bf16x8 hv = *(const bf16x8*)&hs[(size_t)nd * D + sl * 8];   // self term (hs[nd])
    float sum[8], mn[8], mx[8];
    #pragma unroll
    for (int q = 0; q < 8; q++) {
      float v = (float)hv[q];
      sum[q] = v; mn[q] = v; mx[q] = v;
    }
    int e0 = rowptr[nd], e1 = rowptr[nd + 1];
    for (int eb = e0; eb < e1; eb += 16) {
      int rem = e1 - eb; if (rem > 16) rem = 16;
      int le = eb + (sl < rem ? sl : rem - 1);
      int re = csr[le];              // lane sl holds edge sl's source
      int j = 0;
      for (; j + 8 <= rem; j += 8) {
        int r[8]; bf16x8 v[8];
        #pragma unroll
        for (int u = 0; u < 8; u++) r[u] = __shfl(re, j + u, 16);
        #pragma unroll
        for (int u = 0; u < 8; u++) v[u] = *(const bf16x8*)&hs[(size_t)r[u] * D + sl * 8];
        #pragma unroll
        for (int u = 0; u < 8; u++)
          #pragma unroll
          for (int q = 0; q < 8; q++) {
            float a = (float)v[u][q];
            sum[q] += a; mn[q] = fminf(mn[q], a); mx[q] = fmaxf(mx[q], a);
          }
      }
      for (; j + 4 <= rem; j += 4) {
        int r[4]; bf16x8 v[4];
        #pragma unroll
        for (int u = 0; u < 4; u++) r[u] = __shfl(re, j + u, 16);
        #pragma unroll
        for (int u = 0; u < 4; u++) v[u] = *(const bf16x8*)&hs[(size_t)r[u] * D + sl * 8];
        #pragma unroll
        for (int u = 0; u < 4; u++)
          #pragma unroll
          for (int q = 0; q < 8; q++) {
            float a = (float)v[u][q];
            sum[q] += a; mn[q] = fminf(mn[q], a); mx[q] = fmaxf(mx[q], a);
          }
      }
      for (; j < rem; j++) {
        int r0 = __shfl(re, j, 16);
        bf16x8 v0 = *(const bf16x8*)&hs[(size_t)r0 * D + sl * 8];
        #pragma unroll
        for (int q = 0; q < 8; q++) {
          float a = (float)v0[q];
          sum[q] += a; mn[q] = fminf(mn[q], a); mx[q] = fmaxf(mx[q], a);
        }
      }
    }
    // finalize: add = di*S, mean = di^3*S, min/max = di*val
    float ns  = di * di;        // = 1/(deg+1)
    float di3 = di * ns;
    bf16x8 o;
    #pragma unroll
    for (int q = 0; q < 8; q++) o[q] = (__bf16)(sum[q] * di3);
    As[lr * 64 + ((     sl) ^ (lr & 7))] = o;    // mean  (k 0..127)
    #pragma unroll
    for (int q = 0; q < 8; q++) o[q] = (__bf16)(sum[q] * di);
    As[lr * 64 + ((16 + sl) ^ (lr & 7))] = o;    // add   (k 128..255)
    #pragma unroll
    for (int q = 0; q < 8; q++) o[q] = (__bf16)(mn[q] * di);
    As[lr * 64 + ((32 + sl) ^ (lr & 7))] = o;    // min   (k 256..383)
    #pragma unroll
    for (int q = 0; q < 8; q++) o[q] = (__bf16)(mx[q] * di);
    As[lr * 64 + ((48 + sl) ^ (lr & 7))] = o;    // max   (k 384..511)
  }

  // ---- phase 2: combine GEMM ----
  f32x4 acc[2][2];   // wave wid: cols wid*32 + n*16; rows m*16
  #pragma unroll
  for (int m = 0; m < 2; m++)
    #pragma unroll
    for (int n = 0; n < 2; n++) acc[m][n] = (f32x4){0.f, 0.f, 0.f, 0.f};

  for (int k0 = 0; k0 < 512; k0 += 64) {
    __syncthreads();
    // stage B tile: 128 cols x 64 k
    #pragma unroll
    for (int c = 0; c < 4; c++) {
      int id = t + c * 256;            // 0..1023
      int cc = id >> 3, kq = id & 7;
      Bs[cc * 8 + (kq ^ (cc & 7))] = *(const bf16x8*)&CW[(size_t)cc * 512 + k0 + kq * 8];
    }
    __syncthreads();
    #pragma unroll
    for (int ks = 0; ks < 2; ks++) {
      bf16x8 a[2], b[2];
      #pragma unroll
      for (int m = 0; m < 2; m++) {
        int row = m * 16 + (lane & 15);
        int qq = (k0 >> 3) + ks * 4 + (lane >> 4);
        a[m] = As[row * 64 + (qq ^ (row & 7))];
      }
      #pragma unroll
      for (int n = 0; n < 2; n++) {
        int cc = wid * 32 + n * 16 + (lane & 15);
        b[n] = Bs[cc * 8 + ((ks * 4 + (lane >> 4)) ^ (cc & 7))];
      }
      #pragma unroll
      for (int m = 0; m < 2; m++)
        #pragma unroll
        for (int n = 0; n < 2; n++)
          acc[m][n] = __builtin_amdgcn_mfma_f32_16x16x32_bf16(a[m], b[n], acc[m][n], 0, 0, 0);
    }
  }

  // epilogue: bias + ReLU -> bf16
  #pragma unroll
  for (int m = 0; m < 2; m++) {
    int rbase = nd0 + m * 16 + (lane >> 4) * 4;
    #pragma unroll
    for (int n = 0; n < 2; n++) {
      int cc = wid * 32 + n * 16 + (lane & 15);
      float bv = bias[cc];
      #pragma unroll
      for (int j = 0; j < 4; j++) {
        float v = fmaxf(acc[m][n][j] + bv, 0.f);
        out[(size_t)(rbase + j) * 128 + cc] = (__bf16)v;
      }
    }
  }
}

// ---------------- MFMA head + fused log_softmax ----------------
__global__ __launch_bounds__(256) void k_head(const __bf16* __restrict__ h,
                                              const __bf16* __restrict__ Whi,  // [40][128]
                                              const __bf16* __restrict__ Wlo,
                                              const float* __restrict__ bias,
                                              float* __restrict__ out) {
  __shared__ bf16x8 Ah[64 * 16];                // 64 rows x 128 k
  __shared__ bf16x8 Bh[48 * 16], Bl[48 * 16];   // 48 rows (pad) x 128 k
  int t = threadIdx.x;
  int lane = t & 63, wid = t >> 6;
  int row0 = blockIdx.x * 64;                    // 625 * 64 == 40000

  #pragma unroll
  for (int c = 0; c < 4; c++) {
    int id = t + c * 256;
    int r = id >> 4, q = id & 15;
    int ch = r * 16 + (q ^ (r & 15));
    Ah[ch] = *(const bf16x8*)&h[(size_t)(row0 + r) * D + q * 8];
  }
  #pragma unroll
  for (int c = 0; c < 3; c++) {
    int id = t + c * 256;
    int r = id >> 4, q = id & 15;
    int ch = r * 16 + (q ^ (r & 15));
    bf16x8 hi = {}, lo = {};
    if (r < NCLS) {
      hi = *(const bf16x8*)&Whi[(size_t)r * D + q * 8];
      lo = *(const bf16x8*)&Wlo[(size_t)r * D + q * 8];
    }
    Bh[ch] = hi; Bl[ch] = lo;
  }
  __syncthreads();

  f32x4 acc[3];
  #pragma unroll
  for (int n = 0; n < 3; n++) acc[n] = (f32x4){0.f, 0.f, 0.f, 0.f};
  #pragma unroll
  for (int ks = 0; ks < 4; ks++) {
    int arow = wid * 16 + (lane & 15);
    int ach = arow * 16 + ((ks * 4 + (lane >> 4)) ^ (arow & 15));
    bf16x8 ah = Ah[ach];
    #pragma unroll
    for (int n = 0; n < 3; n++) {
      int brow = n * 16 + (lane & 15);
      int bch = brow * 16 + ((ks * 4 + (lane >> 4)) ^ (brow & 15));
      bf16x8 bh = Bh[bch], bl = Bl[bch];
      acc[n] = __builtin_amdgcn_mfma_f32_16x16x32_bf16(ah, bh, acc[n], 0, 0, 0);
      acc[n] = __builtin_amdgcn_mfma_f32_16x16x32_bf16(ah, bl, acc[n], 0, 0, 0);
    }
  }

  int cl = lane & 15;
  float bb[3];
  #pragma unroll
  for (int n = 0; n < 3; n++) {
    int c = n * 16 + cl;
    bb[n] = (c < NCLS) ? bias[c] : 0.f;
  }
  #pragma unroll
  for (int j = 0; j < 4; j++) {
    float v[3];
    #pragma unroll
    for (int n = 0; n < 3; n++) {
      int c = n * 16 + cl;
      v[n] = (c < NCLS) ? acc[n][j] + bb[n] : -INFINITY;
    }
    float m = fmaxf(fmaxf(v[0], v[1]), v[2]);
    #pragma unroll
    for (int off = 1; off < 16; off <<= 1) m = fmaxf(m, __shfl_xor(m, off, 16));
    float s = 0.f;
    #pragma unroll
    for (int n = 0; n < 3; n++) {
      int c = n * 16 + cl;
      if (c < NCLS) s += expf(v[n] - m);
    }
    #pragma unroll
    for (int off = 1; off < 16; off <<= 1) s += __shfl_xor(s, off, 16);
    float ls = logf(s);
    int row = row0 + wid * 16 + (lane >> 4) * 4 + j;
    #pragma unroll
    for (int n = 0; n < 3; n++) {
      int c = n * 16 + cl;
      if (c < NCLS) out[(size_t)row * NCLS + c] = v[n] - m - ls;
    }
  }
}

// ---------------- launch ----------------
extern "C" void kernel_launch(void* const* d_in, const int* in_sizes, int n_in,
                              void* d_out, int out_size, void* d_ws, size_t ws_size,
                              hipStream_t stream) {
  const float* x    = (const float*)d_in[0];
  const int*   ei   = (const int*)  d_in[1];
  const float* W0   = (const float*)d_in[2];
  const float* C0   = (const float*)d_in[3];
  const float* b0   = (const float*)d_in[4];
  const float* W1   = (const float*)d_in[5];
  const float* C1   = (const float*)d_in[6];
  const float* b1   = (const float*)d_in[7];
  const float* Wout = (const float*)d_in[8];
  const float* bout = (const float*)d_in[9];
  float* out = (float*)d_out;

  char* ws = (char*)d_ws;
  size_t o = 0;
  auto take = [&](size_t bytes) -> char* {
    char* p = ws + o;
    o += (bytes + 255) & ~(size_t)255;
    return p;
  };
  int*    deg    = (int*)   take((size_t)NN * 4);
  int*    rowptr = (int*)   take((size_t)(NN + 1) * 4);
  int*    cursor = (int*)   take((size_t)NN * 4);
  int*    bsum   = (int*)   take(64 * 4);
  int*    csr    = (int*)   take((size_t)NE * 4);
  float*  dinv   = (float*) take((size_t)NN * 4);
  __bf16* Whi0   = (__bf16*)take(128 * 128 * 2);
  __bf16* Wlo0   = (__bf16*)take(128 * 128 * 2);
  __bf16* Chi0   = (__bf16*)take(128 * 512 * 2);
  __bf16* Clo0   = (__bf16*)take(128 * 512 * 2);
  __bf16* Whi1   = (__bf16*)take(128 * 128 * 2);
  __bf16* Wlo1   = (__bf16*)take(128 * 128 * 2);
  __bf16* Chi1   = (__bf16*)take(128 * 512 * 2);
  __bf16* Clo1   = (__bf16*)take(128 * 512 * 2);
  __bf16* Ohi    = (__bf16*)take(40 * 128 * 2);
  __bf16* Olo    = (__bf16*)take(40 * 128 * 2);
  __bf16* bufA   = (__bf16*)take((size_t)NN * 128 * 2);   // hs (pre-scaled), bf16
  __bf16* bufC   = (__bf16*)take((size_t)NN * 128 * 2);   // layer out, bf16

  const int* row = ei;        // edge_index[0]
  const int* col = ei + NE;   // edge_index[1]

  // fused zero + weight split
  k_prep<<<cdiv(168960, 256), 256, 0, stream>>>(deg,
                                                W0, Whi0, Wlo0, C0, Chi0, Clo0,
                                                W1, Whi1, Wlo1, C1, Chi1, Clo1,
                                                Wout, Ohi, Olo);
  // CSR by destination
  k_count<<<cdiv(NE, 256), 256, 0, stream>>>(col, deg);
  k_scan1<<<40, 256, 0, stream>>>(deg, rowptr, bsum);
  k_scan2<<<1, 64, 0, stream>>>(bsum, 40, rowptr + NN);
  k_scan3<<<cdiv(NN, 256), 256, 0, stream>>>(rowptr, bsum, deg, cursor, dinv);
  k_fill<<<cdiv(NE, 256), 256, 0, stream>>>(row, col, cursor, csr);

  // layer 0
  k_lin<true ><<<625, 256, 0, stream>>>(x,    Whi0, Wlo0, dinv, bufA);
  k_aggcomb<<<1250, 256, 0, stream>>>(bufA, rowptr, csr, dinv, Chi0, b0, bufC);
  // layer 1
  k_lin<false><<<625, 256, 0, stream>>>(bufC, Whi1, Wlo1, dinv, bufA);
  k_aggcomb<<<1250, 256, 0, stream>>>(bufA, rowptr, csr, dinv, Chi1, b1, bufC);
  // head + log_softmax
  k_head<<<625, 256, 0, stream>>>(bufC, Ohi, Olo, bout, out);
}

// Round 8
// 184.393 us; speedup vs baseline: 2.6860x; 1.0157x over previous
//
#include <hip/hip_runtime.h>
#include <hip/hip_bf16.h>
#include <math.h>

#define NN 40000
#define NE 640000
#define D 128
#define NCLS 40

typedef __bf16 bf16x8 __attribute__((ext_vector_type(8)));
typedef float  f32x4  __attribute__((ext_vector_type(4)));

static inline int cdiv(int a, int b){ return (a + b - 1) / b; }

// ---------------- setup kernels ----------------

// fused: zero deg + split all 5 weight tensors fp32 -> bf16 hi/lo
__global__ __launch_bounds__(256) void k_prep(int* __restrict__ deg,
                                              const float* __restrict__ W0, __bf16* h0, __bf16* l0,
                                              const float* __restrict__ C0, __bf16* h1, __bf16* l1,
                                              const float* __restrict__ W1, __bf16* h2, __bf16* l2,
                                              const float* __restrict__ C1, __bf16* h3, __bf16* l3,
                                              const float* __restrict__ WO, __bf16* h4, __bf16* l4) {
  int i = blockIdx.x * 256 + threadIdx.x;
  if (i < NN) deg[i] = 0;
  const float* src; __bf16* dh; __bf16* dl; int off;
  if      (i < 16384)  { src = W0; dh = h0; dl = l0; off = i; }
  else if (i < 81920)  { src = C0; dh = h1; dl = l1; off = i - 16384; }
  else if (i < 98304)  { src = W1; dh = h2; dl = l2; off = i - 81920; }
  else if (i < 163840) { src = C1; dh = h3; dl = l3; off = i - 98304; }
  else if (i < 168960) { src = WO; dh = h4; dl = l4; off = i - 163840; }
  else return;
  float v = src[off];
  __bf16 h = (__bf16)v;
  dh[off] = h;
  dl[off] = (__bf16)(v - (float)h);
}

__global__ __launch_bounds__(256) void k_count(const int* __restrict__ col,
                                               int* __restrict__ deg) {
  int i = blockIdx.x * 256 + threadIdx.x;
  if (i < NE) atomicAdd(&deg[col[i]], 1);
}

__global__ __launch_bounds__(256) void k_scan1(const int* __restrict__ cnt,
                                               int* __restrict__ excl,
                                               int* __restrict__ bsum) {
  __shared__ int sh[256];
  int b = blockIdx.x, t = threadIdx.x;
  int base = b * 1024 + t * 4;
  int v0 = (base + 0 < NN) ? cnt[base + 0] : 0;
  int v1 = (base + 1 < NN) ? cnt[base + 1] : 0;
  int v2 = (base + 2 < NN) ? cnt[base + 2] : 0;
  int v3 = (base + 3 < NN) ? cnt[base + 3] : 0;
  sh[t] = v0 + v1 + v2 + v3;
  __syncthreads();
  for (int off = 1; off < 256; off <<= 1) {
    int x = (t >= off) ? sh[t - off] : 0;
    __syncthreads();
    sh[t] += x;
    __syncthreads();
  }
  int pre = (t > 0) ? sh[t - 1] : 0;
  if (base + 0 < NN) excl[base + 0] = pre;  pre += v0;
  if (base + 1 < NN) excl[base + 1] = pre;  pre += v1;
  if (base + 2 < NN) excl[base + 2] = pre;  pre += v2;
  if (base + 3 < NN) excl[base + 3] = pre;
  if (t == 255) bsum[b] = sh[255];
}

__global__ void k_scan2(int* __restrict__ bsum, int nb, int* __restrict__ total_out) {
  int t = threadIdx.x;  // 64 threads
  __shared__ int sh[64];
  sh[t] = (t < nb) ? bsum[t] : 0;
  __syncthreads();
  if (t == 0) {
    int run = 0;
    for (int i = 0; i < nb; i++) { int v = sh[i]; sh[i] = run; run += v; }
    *total_out = run;
  }
  __syncthreads();
  if (t < nb) bsum[t] = sh[t];
}

__global__ __launch_bounds__(256) void k_scan3(int* __restrict__ rowptr,
                                               const int* __restrict__ bsum,
                                               const int* __restrict__ deg,
                                               int* __restrict__ cursor,
                                               float* __restrict__ dinv) {
  int i = blockIdx.x * 256 + threadIdx.x;
  if (i < NN) {
    int v = rowptr[i] + bsum[i >> 10];
    rowptr[i] = v;
    cursor[i] = v;
    dinv[i] = rsqrtf((float)(deg[i] + 1));
  }
}

__global__ __launch_bounds__(256) void k_fill(const int* __restrict__ row,
                                              const int* __restrict__ col,
                                              int* __restrict__ cursor,
                                              int* __restrict__ csr) {
  int i = blockIdx.x * 256 + threadIdx.x;
  if (i < NE) {
    int c = col[i];
    int p = atomicAdd(&cursor[c], 1);
    csr[p] = row[i];
  }
}

// ---------------- lin GEMM: hs[m][n] = dinv[m] * sum_k A[m][k] * W[n][k] ----------------
// K = 128. A fp32 (AFP32) or bf16. W hi+lo (2 MFMAs). Output bf16, row-scaled by dinv.
template<bool AFP32>
__global__ __launch_bounds__(256) void k_lin(const void* __restrict__ Av,
                                             const __bf16* __restrict__ BhG,
                                             const __bf16* __restrict__ BlG,
                                             const float* __restrict__ rowscale,
                                             __bf16* __restrict__ out) {
  __shared__ bf16x8 Ah[64 * 8];
  __shared__ bf16x8 Bh[128 * 8], Bl[128 * 8];
  int t = threadIdx.x;
  int lane = t & 63, wid = t >> 6;
  int wr = wid >> 1, wc = wid & 1;
  int row0 = blockIdx.x * 64;            // 625 * 64 == 40000

  f32x4 acc[2][4];
  #pragma unroll
  for (int m = 0; m < 2; m++)
    #pragma unroll
    for (int n = 0; n < 4; n++) acc[m][n] = (f32x4){0.f, 0.f, 0.f, 0.f};

  for (int k0 = 0; k0 < 128; k0 += 64) {
    __syncthreads();
    #pragma unroll
    for (int c = 0; c < 2; c++) {
      int id = t + c * 256;              // 0..511
      int r = id >> 3, q = id & 7;
      int ch = r * 8 + (q ^ (r & 7));
      if constexpr (AFP32) {
        const float* A = (const float*)Av;
        const float* src = &A[(size_t)(row0 + r) * 128 + k0 + q * 8];
        float4 v0 = *(const float4*)src;
        float4 v1 = *(const float4*)(src + 4);
        float vv[8] = {v0.x, v0.y, v0.z, v0.w, v1.x, v1.y, v1.z, v1.w};
        bf16x8 hi;
        #pragma unroll
        for (int j = 0; j < 8; j++) hi[j] = (__bf16)vv[j];
        Ah[ch] = hi;
      } else {
        const __bf16* A = (const __bf16*)Av;
        Ah[ch] = *(const bf16x8*)&A[(size_t)(row0 + r) * 128 + k0 + q * 8];
      }
    }
    #pragma unroll
    for (int c = 0; c < 4; c++) {
      int id = t + c * 256;              // 0..1023
      int r = id >> 3, q = id & 7;
      int ch = r * 8 + (q ^ (r & 7));
      Bh[ch] = *(const bf16x8*)&BhG[(size_t)r * 128 + k0 + q * 8];
      Bl[ch] = *(const bf16x8*)&BlG[(size_t)r * 128 + k0 + q * 8];
    }
    __syncthreads();
    #pragma unroll
    for (int ks = 0; ks < 2; ks++) {
      bf16x8 ah[2], bh[4], bl[4];
      #pragma unroll
      for (int m = 0; m < 2; m++) {
        int row = wr * 32 + m * 16 + (lane & 15);
        int ch = row * 8 + ((ks * 4 + (lane >> 4)) ^ (row & 7));
        ah[m] = Ah[ch];
      }
      #pragma unroll
      for (int n = 0; n < 4; n++) {
        int row = wc * 64 + n * 16 + (lane & 15);
        int ch = row * 8 + ((ks * 4 + (lane >> 4)) ^ (row & 7));
        bh[n] = Bh[ch]; bl[n] = Bl[ch];
      }
      #pragma unroll
      for (int m = 0; m < 2; m++)
        #pragma unroll
        for (int n = 0; n < 4; n++) {
          acc[m][n] = __builtin_amdgcn_mfma_f32_16x16x32_bf16(ah[m], bh[n], acc[m][n], 0, 0, 0);
          acc[m][n] = __builtin_amdgcn_mfma_f32_16x16x32_bf16(ah[m], bl[n], acc[m][n], 0, 0, 0);
        }
    }
  }

  #pragma unroll
  for (int m = 0; m < 2; m++) {
    int rbase = row0 + wr * 32 + m * 16 + (lane >> 4) * 4;
    float rs[4];
    #pragma unroll
    for (int j = 0; j < 4; j++) rs[j] = rowscale[rbase + j];
    #pragma unroll
    for (int n = 0; n < 4; n++) {
      int col = wc * 64 + n * 16 + (lane & 15);
      #pragma unroll
      for (int j = 0; j < 4; j++)
        out[(size_t)(rbase + j) * 128 + col] = (__bf16)(acc[m][n][j] * rs[j]);
    }
  }
}

// ---------------- fused aggregate + combine GEMM + bias + ReLU ----------------
// Per block: 32 nodes. Phase 1: gather pre-scaled hs rows, reduce sum/min/max;
// store [add|min|max]*di (384 k) into As. Mean-fold: mean = di^2 * add per row,
// so its GEMM contribution is computed from the SAME add block into a separate
// accumulator and scaled by di^2 in the epilogue. LDS 24+16=40KB -> 4 blocks/CU.
__global__ __launch_bounds__(256, 4) void k_aggcomb(const __bf16* __restrict__ hs,
                                                    const int* __restrict__ rowptr,
                                                    const int* __restrict__ csr,
                                                    const float* __restrict__ dinv,
                                                    const __bf16* __restrict__ CW,   // [128][512]
                                                    const float* __restrict__ bias,
                                                    __bf16* __restrict__ out) {
  __shared__ bf16x8 As[32 * 48];   // 32 rows x 384 k (add|min|max); chunk = r*48 + (qq ^ (r&7))
  __shared__ bf16x8 Bs[128 * 8];   // 128 cols x 64 k per K-tile
  int t = threadIdx.x;
  int lane = t & 63, wid = t >> 6;
  int g = t >> 4;                  // 16 groups of 16 lanes
  int sl = t & 15;                 // features sl*8 .. sl*8+7
  int nd0 = blockIdx.x * 32;       // 1250 blocks * 32 == 40000

  // ---- phase 1: aggregation (group g does local rows g and g+16) ----
  #pragma unroll
  for (int rep = 0; rep < 2; rep++) {
    int lr = g + rep * 16;
    int nd = nd0 + lr;
    float di = dinv[nd];
    bf16x8 hv = *(const bf16x8*)&hs[(size_t)nd * D + sl * 8];   // self term
    float sum[8], mn[8], mx[8];
    #pragma unroll
    for (int q = 0; q < 8; q++) {
      float v = (float)hv[q];
      sum[q] = v; mn[q] = v; mx[q] = v;
    }
    int e0 = rowptr[nd], e1 = rowptr[nd + 1];
    for (int eb = e0; eb < e1; eb += 16) {
      int rem = e1 - eb; if (rem > 16) rem = 16;
      int le = eb + (sl < rem ? sl : rem - 1);
      int re = csr[le];              // lane sl holds edge sl's source
      int j = 0;
      for (; j + 8 <= rem; j += 8) {
        int r[8]; bf16x8 v[8];
        #pragma unroll
        for (int u = 0; u < 8; u++) r[u] = __shfl(re, j + u, 16);
        #pragma unroll
        for (int u = 0; u < 8; u++) v[u] = *(const bf16x8*)&hs[(size_t)r[u] * D + sl * 8];
        #pragma unroll
        for (int u = 0; u < 8; u++)
          #pragma unroll
          for (int q = 0; q < 8; q++) {
            float a = (float)v[u][q];
            sum[q] += a; mn[q] = fminf(mn[q], a); mx[q] = fmaxf(mx[q], a);
          }
      }
      for (; j + 4 <= rem; j += 4) {
        int r[4]; bf16x8 v[4];
        #pragma unroll
        for (int u = 0; u < 4; u++) r[u] = __shfl(re, j + u, 16);
        #pragma unroll
        for (int u = 0; u < 4; u++) v[u] = *(const bf16x8*)&hs[(size_t)r[u] * D + sl * 8];
        #pragma unroll
        for (int u = 0; u < 4; u++)
          #pragma unroll
          for (int q = 0; q < 8; q++) {
            float a = (float)v[u][q];
            sum[q] += a; mn[q] = fminf(mn[q], a); mx[q] = fmaxf(mx[q], a);
          }
      }
      for (; j < rem; j++) {
        int r0 = __shfl(re, j, 16);
        bf16x8 v0 = *(const bf16x8*)&hs[(size_t)r0 * D + sl * 8];
        #pragma unroll
        for (int q = 0; q < 8; q++) {
          float a = (float)v0[q];
          sum[q] += a; mn[q] = fminf(mn[q], a); mx[q] = fmaxf(mx[q], a);
        }
      }
    }
    // store add|min|max scaled by di (mean handled via fold in epilogue)
    bf16x8 o;
    #pragma unroll
    for (int q = 0; q < 8; q++) o[q] = (__bf16)(sum[q] * di);
    As[lr * 48 + ((     sl) ^ (lr & 7))] = o;    // add (storage k 0..127)
    #pragma unroll
    for (int q = 0; q < 8; q++) o[q] = (__bf16)(mn[q] * di);
    As[lr * 48 + ((16 + sl) ^ (lr & 7))] = o;    // min (storage k 128..255)
    #pragma unroll
    for (int q = 0; q < 8; q++) o[q] = (__bf16)(mx[q] * di);
    As[lr * 48 + ((32 + sl) ^ (lr & 7))] = o;    // max (storage k 256..383)
  }

  // ---- phase 2: combine GEMM ----
  // GEMM k 0..127: mean contribution (A = add block) -> accM (scaled by di^2 later)
  // GEMM k 128..255: add (A = add block); 256..383: min; 384..511: max -> accA
  f32x4 accA[2][2], accM[2][2];
  #pragma unroll
  for (int m = 0; m < 2; m++)
    #pragma unroll
    for (int n = 0; n < 2; n++) {
      accA[m][n] = (f32x4){0.f, 0.f, 0.f, 0.f};
      accM[m][n] = (f32x4){0.f, 0.f, 0.f, 0.f};
    }

  for (int k0 = 0; k0 < 512; k0 += 64) {
    __syncthreads();
    #pragma unroll
    for (int c = 0; c < 4; c++) {
      int id = t + c * 256;            // 0..1023
      int cc = id >> 3, kq = id & 7;
      Bs[cc * 8 + (kq ^ (cc & 7))] = *(const bf16x8*)&CW[(size_t)cc * 512 + k0 + kq * 8];
    }
    __syncthreads();
    int se = (k0 < 256) ? (k0 & 127) : (k0 - 128);   // A storage element base
    int qbase = se >> 3;
    bool isMean = (k0 < 128);
    #pragma unroll
    for (int ks = 0; ks < 2; ks++) {
      bf16x8 a[2], b[2];
      #pragma unroll
      for (int m = 0; m < 2; m++) {
        int row = m * 16 + (lane & 15);
        int qq = qbase + ks * 4 + (lane >> 4);
        a[m] = As[row * 48 + (qq ^ (row & 7))];
      }
      #pragma unroll
      for (int n = 0; n < 2; n++) {
        int cc = wid * 32 + n * 16 + (lane & 15);
        b[n] = Bs[cc * 8 + ((ks * 4 + (lane >> 4)) ^ (cc & 7))];
      }
      #pragma unroll
      for (int m = 0; m < 2; m++)
        #pragma unroll
        for (int n = 0; n < 2; n++) {
          if (isMean)
            accM[m][n] = __builtin_amdgcn_mfma_f32_16x16x32_bf16(a[m], b[n], accM[m][n], 0, 0, 0);
          else
            accA[m][n] = __builtin_amdgcn_mfma_f32_16x16x32_bf16(a[m], b[n], accA[m][n], 0, 0, 0);
        }
    }
  }

  // epilogue: out = accA + di^2*accM + bias, ReLU -> bf16
  #pragma unroll
  for (int m = 0; m < 2; m++) {
    int rbase = nd0 + m * 16 + (lane >> 4) * 4;
    float d2[4];
    #pragma unroll
    for (int j = 0; j < 4; j++) {
      float dv = dinv[rbase + j];
      d2[j] = dv * dv;
    }
    #pragma unroll
    for (int n = 0; n < 2; n++) {
      int cc = wid * 32 + n * 16 + (lane & 15);
      float bv = bias[cc];
      #pragma unroll
      for (int j = 0; j < 4; j++) {
        float v = fmaxf(accA[m][n][j] + d2[j] * accM[m][n][j] + bv, 0.f);
        out[(size_t)(rbase + j) * 128 + cc] = (__bf16)v;
      }
    }
  }
}

// ---------------- MFMA head + fused log_softmax ----------------
__global__ __launch_bounds__(256) void k_head(const __bf16* __restrict__ h,
                                              const __bf16* __restrict__ Whi,  // [40][128]
                                              const __bf16* __restrict__ Wlo,
                                              const float* __restrict__ bias,
                                              float* __restrict__ out) {
  __shared__ bf16x8 Ah[64 * 16];                // 64 rows x 128 k
  __shared__ bf16x8 Bh[48 * 16], Bl[48 * 16];   // 48 rows (pad) x 128 k
  int t = threadIdx.x;
  int lane = t & 63, wid = t >> 6;
  int row0 = blockIdx.x * 64;                    // 625 * 64 == 40000

  #pragma unroll
  for (int c = 0; c < 4; c++) {
    int id = t + c * 256;
    int r = id >> 4, q = id & 15;
    int ch = r * 16 + (q ^ (r & 15));
    Ah[ch] = *(const bf16x8*)&h[(size_t)(row0 + r) * D + q * 8];
  }
  #pragma unroll
  for (int c = 0; c < 3; c++) {
    int id = t + c * 256;
    int r = id >> 4, q = id & 15;
    int ch = r * 16 + (q ^ (r & 15));
    bf16x8 hi = {}, lo = {};
    if (r < NCLS) {
      hi = *(const bf16x8*)&Whi[(size_t)r * D + q * 8];
      lo = *(const bf16x8*)&Wlo[(size_t)r * D + q * 8];
    }
    Bh[ch] = hi; Bl[ch] = lo;
  }
  __syncthreads();

  f32x4 acc[3];
  #pragma unroll
  for (int n = 0; n < 3; n++) acc[n] = (f32x4){0.f, 0.f, 0.f, 0.f};
  #pragma unroll
  for (int ks = 0; ks < 4; ks++) {
    int arow = wid * 16 + (lane & 15);
    int ach = arow * 16 + ((ks * 4 + (lane >> 4)) ^ (arow & 15));
    bf16x8 ah = Ah[ach];
    #pragma unroll
    for (int n = 0; n < 3; n++) {
      int brow = n * 16 + (lane & 15);
      int bch = brow * 16 + ((ks * 4 + (lane >> 4)) ^ (brow & 15));
      bf16x8 bh = Bh[bch], bl = Bl[bch];
      acc[n] = __builtin_amdgcn_mfma_f32_16x16x32_bf16(ah, bh, acc[n], 0, 0, 0);
      acc[n] = __builtin_amdgcn_mfma_f32_16x16x32_bf16(ah, bl, acc[n], 0, 0, 0);
    }
  }

  int cl = lane & 15;
  float bb[3];
  #pragma unroll
  for (int n = 0; n < 3; n++) {
    int c = n * 16 + cl;
    bb[n] = (c < NCLS) ? bias[c] : 0.f;
  }
  #pragma unroll
  for (int j = 0; j < 4; j++) {
    float v[3];
    #pragma unroll
    for (int n = 0; n < 3; n++) {
      int c = n * 16 + cl;
      v[n] = (c < NCLS) ? acc[n][j] + bb[n] : -INFINITY;
    }
    float m = fmaxf(fmaxf(v[0], v[1]), v[2]);
    #pragma unroll
    for (int off = 1; off < 16; off <<= 1) m = fmaxf(m, __shfl_xor(m, off, 16));
    float s = 0.f;
    #pragma unroll
    for (int n = 0; n < 3; n++) {
      int c = n * 16 + cl;
      if (c < NCLS) s += expf(v[n] - m);
    }
    #pragma unroll
    for (int off = 1; off < 16; off <<= 1) s += __shfl_xor(s, off, 16);
    float ls = logf(s);
    int row = row0 + wid * 16 + (lane >> 4) * 4 + j;
    #pragma unroll
    for (int n = 0; n < 3; n++) {
      int c = n * 16 + cl;
      if (c < NCLS) out[(size_t)row * NCLS + c] = v[n] - m - ls;
    }
  }
}

// ---------------- launch ----------------
extern "C" void kernel_launch(void* const* d_in, const int* in_sizes, int n_in,
                              void* d_out, int out_size, void* d_ws, size_t ws_size,
                              hipStream_t stream) {
  const float* x    = (const float*)d_in[0];
  const int*   ei   = (const int*)  d_in[1];
  const float* W0   = (const float*)d_in[2];
  const float* C0   = (const float*)d_in[3];
  const float* b0   = (const float*)d_in[4];
  const float* W1   = (const float*)d_in[5];
  const float* C1   = (const float*)d_in[6];
  const float* b1   = (const float*)d_in[7];
  const float* Wout = (const float*)d_in[8];
  const float* bout = (const float*)d_in[9];
  float* out = (float*)d_out;

  char* ws = (char*)d_ws;
  size_t o = 0;
  auto take = [&](size_t bytes) -> char* {
    char* p = ws + o;
    o += (bytes + 255) & ~(size_t)255;
    return p;
  };
  int*    deg    = (int*)   take((size_t)NN * 4);
  int*    rowptr = (int*)   take((size_t)(NN + 1) * 4);
  int*    cursor = (int*)   take((size_t)NN * 4);
  int*    bsum   = (int*)   take(64 * 4);
  int*    csr    = (int*)   take((size_t)NE * 4);
  float*  dinv   = (float*) take((size_t)NN * 4);
  __bf16* Whi0   = (__bf16*)take(128 * 128 * 2);
  __bf16* Wlo0   = (__bf16*)take(128 * 128 * 2);
  __bf16* Chi0   = (__bf16*)take(128 * 512 * 2);
  __bf16* Clo0   = (__bf16*)take(128 * 512 * 2);
  __bf16* Whi1   = (__bf16*)take(128 * 128 * 2);
  __bf16* Wlo1   = (__bf16*)take(128 * 128 * 2);
  __bf16* Chi1   = (__bf16*)take(128 * 512 * 2);
  __bf16* Clo1   = (__bf16*)take(128 * 512 * 2);
  __bf16* Ohi    = (__bf16*)take(40 * 128 * 2);
  __bf16* Olo    = (__bf16*)take(40 * 128 * 2);
  __bf16* bufA   = (__bf16*)take((size_t)NN * 128 * 2);   // hs (pre-scaled), bf16
  __bf16* bufC   = (__bf16*)take((size_t)NN * 128 * 2);   // layer out, bf16

  const int* row = ei;        // edge_index[0]
  const int* col = ei + NE;   // edge_index[1]

  // fused zero + weight split
  k_prep<<<cdiv(168960, 256), 256, 0, stream>>>(deg,
                                                W0, Whi0, Wlo0, C0, Chi0, Clo0,
                                                W1, Whi1, Wlo1, C1, Chi1, Clo1,
                                                Wout, Ohi, Olo);
  // CSR by destination
  k_count<<<cdiv(NE, 256), 256, 0, stream>>>(col, deg);
  k_scan1<<<40, 256, 0, stream>>>(deg, rowptr, bsum);
  k_scan2<<<1, 64, 0, stream>>>(bsum, 40, rowptr + NN);
  k_scan3<<<cdiv(NN, 256), 256, 0, stream>>>(rowptr, bsum, deg, cursor, dinv);
  k_fill<<<cdiv(NE, 256), 256, 0, stream>>>(row, col, cursor, csr);

  // layer 0
  k_lin<true ><<<625, 256, 0, stream>>>(x,    Whi0, Wlo0, dinv, bufA);
  k_aggcomb<<<1250, 256, 0, stream>>>(bufA, rowptr, csr, dinv, Chi0, b0, bufC);
  // layer 1
  k_lin<false><<<625, 256, 0, stream>>>(bufC, Whi1, Wlo1, dinv, bufA);
  k_aggcomb<<<1250, 256, 0, stream>>>(bufA, rowptr, csr, dinv, Chi1, b1, bufC);
  // head + log_softmax
  k_head<<<625, 256, 0, stream>>>(bufC, Ohi, Olo, bout, out);
}